// Round 2
// baseline (431.257 us; speedup 1.0000x reference)
//
#include <hip/hip_runtime.h>
#include <stdint.h>

// Problem constants
#define L_SEQ 2048
#define BATCH 2
#define DIM   1024
#define NH    16
#define HDIM  64
#define DFF_  4096
#define ROWS  (L_SEQ*BATCH)   // 4096 token rows, row index = l*BATCH + b

// softmax scale folded into Q at split time: (1/sqrt(64)) * log2(e)
#define QSCALE 0.18033688011112042f

typedef __attribute__((ext_vector_type(8))) short  bf16x8;
typedef __attribute__((ext_vector_type(4))) float  floatx4;

__device__ __forceinline__ unsigned short f2bf(float f) {
    union { float f; uint32_t u; } x; x.f = f;
    uint32_t r = x.u + 0x7fffu + ((x.u >> 16) & 1u);   // RNE
    return (unsigned short)(r >> 16);
}
__device__ __forceinline__ float bf2f(unsigned short b) {
    union { uint32_t u; float f; } x; x.u = ((uint32_t)b) << 16;
    return x.f;
}
__device__ __forceinline__ uint32_t fbits(float f) {
    union { float f; uint32_t u; } x; x.f = f; return x.u;
}

// async global->LDS, 16B per lane; lds dest = wave-uniform base + lane*16
__device__ __forceinline__ void load_lds16(const unsigned short* g, unsigned short* l) {
    __builtin_amdgcn_global_load_lds(
        (const __attribute__((address_space(1))) unsigned int*)g,
        (__attribute__((address_space(3))) unsigned int*)l, 16, 0, 0);
}

// ---------------------------------------------------------------------------
// All 4 weight transposes in one kernel: fp32 [K,N] -> bf16 [N,K], 32x32 tiles
// ---------------------------------------------------------------------------
__global__ __launch_bounds__(256)
void transpose_all(const float* __restrict__ s0, unsigned short* __restrict__ d0,
                   const float* __restrict__ s1, unsigned short* __restrict__ d1,
                   const float* __restrict__ s2, unsigned short* __restrict__ d2,
                   const float* __restrict__ s3, unsigned short* __restrict__ d3)
{
    const int id = blockIdx.x;
    const float* src; unsigned short* dst; int K, N, local;
    if (id < 3072)      { src = s0; dst = d0; K = 1024; N = 3072; local = id; }
    else if (id < 4096) { src = s1; dst = d1; K = 1024; N = 1024; local = id - 3072; }
    else if (id < 8192) { src = s2; dst = d2; K = 1024; N = 4096; local = id - 4096; }
    else                { src = s3; dst = d3; K = 4096; N = 1024; local = id - 8192; }
    const int nN = N >> 5;
    const int bk = (local / nN) * 32, bn = (local % nN) * 32;

    __shared__ float tile[32][36];
    const int t = threadIdx.x;
    const int r = t >> 3, c4 = (t & 7) * 4;
    *(float4*)&tile[r][c4] = *(const float4*)(src + (size_t)(bk + r) * N + bn + c4);
    __syncthreads();
    ushort4 o;
    o.x = f2bf(tile[c4 + 0][r]);
    o.y = f2bf(tile[c4 + 1][r]);
    o.z = f2bf(tile[c4 + 2][r]);
    o.w = f2bf(tile[c4 + 3][r]);
    *(ushort4*)(dst + (size_t)(bn + r) * K + bk + c4) = o;
}

// ---------------------------------------------------------------------------
// LayerNorm: [4096,1024] fp32 or bf16 input -> bf16 out, one block per row
// ---------------------------------------------------------------------------
template<int INBF16>
__global__ __launch_bounds__(256)
void ln_rows(const void* __restrict__ xin, const float* __restrict__ g,
             const float* __restrict__ bta, unsigned short* __restrict__ out)
{
    const int row = blockIdx.x;
    const int t = threadIdx.x;
    float4 v;
    if (INBF16) {
        const ushort4 u = ((const ushort4*)((const unsigned short*)xin + (size_t)row * DIM))[t];
        v.x = bf2f(u.x); v.y = bf2f(u.y); v.z = bf2f(u.z); v.w = bf2f(u.w);
    } else {
        v = ((const float4*)((const float*)xin + (size_t)row * DIM))[t];
    }
    float s  = v.x + v.y + v.z + v.w;
    float s2 = v.x*v.x + v.y*v.y + v.z*v.z + v.w*v.w;
#pragma unroll
    for (int d = 1; d < 64; d <<= 1) { s += __shfl_xor(s, d, 64); s2 += __shfl_xor(s2, d, 64); }
    __shared__ float ss[4], ss2[4];
    const int w = t >> 6, lane = t & 63;
    if (lane == 0) { ss[w] = s; ss2[w] = s2; }
    __syncthreads();
    s  = ss[0] + ss[1] + ss[2] + ss[3];
    s2 = ss2[0] + ss2[1] + ss2[2] + ss2[3];
    const float mu   = s * (1.0f / DIM);
    const float var  = s2 * (1.0f / DIM) - mu * mu;
    const float rstd = rsqrtf(var + 1e-5f);
    const float4 gv = ((const float4*)g)[t];
    const float4 bv = ((const float4*)bta)[t];
    ushort4 o;
    o.x = f2bf((v.x - mu) * rstd * gv.x + bv.x);
    o.y = f2bf((v.y - mu) * rstd * gv.y + bv.y);
    o.z = f2bf((v.z - mu) * rstd * gv.z + bv.z);
    o.w = f2bf((v.w - mu) * rstd * gv.w + bv.w);
    *(ushort4*)(out + (size_t)row * DIM + t * 4) = o;
}

// ---------------------------------------------------------------------------
// bf16 GEMM, B^T input (Bt [N,K]); C = A@B + bias (+resid) (gelu?)
// MI=4: 128x128 tile; MI=2: 64x128 tile. BK=32, m97 structure.
// RESID: 0=none, 1=fp32, 2=bf16
// SPLITK>1: blockIdx.z = K-slice; kz>0 writes raw fp32 partial.
// ---------------------------------------------------------------------------
template<int GELU, int RESID, int OUTBF16, int MI, int SPLITK>
__global__ __launch_bounds__(256)
void gemm_bt(const unsigned short* __restrict__ A,   // [M,K] bf16
             const unsigned short* __restrict__ Bt,  // [N,K] bf16
             const float* __restrict__ bias,         // [N]
             const void* __restrict__ resid,         // [M,N] fp32/bf16 or null
             void* __restrict__ outp,                // bf16 or fp32 [M,N]
             float* __restrict__ part,               // fp32 partials (SPLITK>1)
             int M, int N, int K)
{
    __shared__ unsigned short As[MI * 32 * 32];   // flat, unpadded
    __shared__ unsigned short Bs[128 * 32];
    const int t = threadIdx.x;
    const int w = t >> 6, lane = t & 63;
    const int quad = lane >> 4, l16 = lane & 15;
    const int wm = (w >> 1) * (MI * 16), wn = (w & 1) * 64;
    const int bm = blockIdx.x * (MI * 32), bn = blockIdx.y * 128;

    const int srow = lane >> 2;
    const int scol = (lane & 3) * 8;

    const unsigned short* Ab = A  + (size_t)bm * K;
    const unsigned short* Bb = Bt + (size_t)bn * K;

    floatx4 acc[MI][4] = {};

    const int kspan = (SPLITK > 1) ? (K / SPLITK) : K;
    const int k0    = (SPLITK > 1) ? blockIdx.z * kspan : 0;

    for (int kc = k0; kc < k0 + kspan; kc += 32) {
        __syncthreads();
#pragma unroll
        for (int i = 0; i < MI / 2; ++i) {
            const int r0 = (i * 4 + w) * 16;
            load_lds16(Ab + (size_t)(r0 + srow) * K + kc + scol, As + r0 * 32);
        }
#pragma unroll
        for (int i = 0; i < 2; ++i) {
            const int r0 = (i * 4 + w) * 16;
            load_lds16(Bb + (size_t)(r0 + srow) * K + kc + scol, Bs + r0 * 32);
        }
        __syncthreads();
        bf16x8 af[MI], bf[4];
#pragma unroll
        for (int i = 0; i < MI; ++i) af[i] = *(const bf16x8*)(As + (wm + i*16 + l16) * 32 + quad * 8);
#pragma unroll
        for (int j = 0; j < 4; ++j) bf[j] = *(const bf16x8*)(Bs + (wn + j*16 + l16) * 32 + quad * 8);
#pragma unroll
        for (int i = 0; i < MI; ++i)
#pragma unroll
            for (int j = 0; j < 4; ++j)
                acc[i][j] = __builtin_amdgcn_mfma_f32_16x16x32_bf16(af[i], bf[j], acc[i][j], 0, 0, 0);
    }

    if (SPLITK > 1 && blockIdx.z > 0) {
        float* po = part + (size_t)(blockIdx.z - 1) * ((size_t)M * N);
#pragma unroll
        for (int i = 0; i < MI; ++i)
#pragma unroll
            for (int j = 0; j < 4; ++j) {
                const int col = bn + wn + j*16 + l16;
#pragma unroll
                for (int r = 0; r < 4; ++r) {
                    const int row = bm + wm + i*16 + quad*4 + r;
                    po[(size_t)row * N + col] = acc[i][j][r];
                }
            }
        return;
    }

#pragma unroll
    for (int i = 0; i < MI; ++i) {
#pragma unroll
        for (int j = 0; j < 4; ++j) {
            const int col = bn + wn + j*16 + l16;
            const float bv = bias[col];
#pragma unroll
            for (int r = 0; r < 4; ++r) {
                const int row = bm + wm + i*16 + quad*4 + r;
                float v = acc[i][j][r] + bv;
                if (RESID == 1) v += ((const float*)resid)[(size_t)row * N + col];
                if (RESID == 2) v += bf2f(((const unsigned short*)resid)[(size_t)row * N + col]);
                if (GELU) {
                    const float u = v;
                    float c = 2.302204225929898f * (u + 0.044715f * u * u * u);
                    c = fminf(c, 80.f);
                    const float e = exp2f(c);
                    v = u * (e / (1.0f + e));
                }
                if (OUTBF16) ((unsigned short*)outp)[(size_t)row * N + col] = f2bf(v);
                else         ((float*)outp)[(size_t)row * N + col] = v;
            }
        }
    }
}

// ---------------------------------------------------------------------------
// 256x256-tile 8-phase GEMM (HK-style schedule in plain HIP).
// BK=64, 512 threads = 8 waves (2 M x 4 N), per-wave 128x64 output.
// LDS 128 KiB: 2 dbuf x (A[256][64] + B[256][64]) bf16, st_16x32 XOR-swizzle
// (linear global_load_lds dest + pre-swizzled global source + swizzled read).
// Per K-tile: 4 phases x 16 MFMA; 1 half-tile (2 loads/thread) staged per
// phase; ONE counted s_waitcnt vmcnt(2) per K-tile (never 0 in steady state).
// Requires M%256==0, N%256==0, K%64==0, K>=128, grid%8==0 (all true here).
// ---------------------------------------------------------------------------
#define SWZ(p) ((p) ^ ((((p) >> 9) & 1) << 5))

template<int GELU>
__global__ __launch_bounds__(512)
void gemm256(const unsigned short* __restrict__ A,   // [M,K] bf16
             const unsigned short* __restrict__ Bt,  // [N,K] bf16
             const float* __restrict__ bias,         // [N]
             unsigned short* __restrict__ outp,      // [M,N] bf16
             int M, int N, int K, int nbx)
{
    extern __shared__ unsigned short lds[];          // 65536 elements
    const int t = threadIdx.x;
    const int w = t >> 6, lane = t & 63;
    const int quad = lane >> 4, l16 = lane & 15;
    const int wr = w >> 2, wc = w & 3;

    // bijective XCD swizzle (gridDim.x % 8 == 0 guaranteed by launcher)
    const int nwg = gridDim.x;
    const int cpx = nwg >> 3;
    const int bid = (blockIdx.x & 7) * cpx + (blockIdx.x >> 3);
    const int bm = (bid % nbx) * 256, bn = (bid / nbx) * 256;

    const unsigned short* Ab = A  + (size_t)bm * K;
    const unsigned short* Bb = Bt + (size_t)bn * K;

    // per-thread pre-swizzled staging coords (2 load rounds per half-tile)
    const int q0 = t * 16,        s0 = SWZ(q0);
    const int q1 = (512 + t) * 16, s1 = SWZ(q1);
    const int srow0 = s0 >> 7, scol0 = (s0 & 127) >> 1;
    const int srow1 = s1 >> 7, scol1 = (s1 & 127) >> 1;

    // half ids: 0=B rows[0,128) 1=B[128,256) 2=A[0,128) 3=A[128,256)
    // LDS element layout per buffer cb: A at cb*32768, B at cb*32768+16384.
#define STAGE(cb_, kt_, half_) do {                                                   \
        const unsigned short* sb_ = ((half_) >= 2 ? Ab : Bb)                          \
            + (size_t)(((half_) & 1) * 128) * K + (kt_) * 64;                         \
        unsigned short* db_ = lds + (cb_) * 32768 + ((half_) >= 2 ? 0 : 16384)        \
            + ((half_) & 1) * 8192 + w * 512;                                         \
        load_lds16(sb_ + (size_t)srow0 * K + scol0, db_);                             \
        load_lds16(sb_ + (size_t)srow1 * K + scol1, db_ + 4096);                      \
    } while (0)

#define PHASE_BAR  do { __builtin_amdgcn_s_barrier(); asm volatile("" ::: "memory"); } while (0)
#define CL_PRE  do { asm volatile("s_waitcnt lgkmcnt(0)" ::: "memory"); \
                     __builtin_amdgcn_sched_barrier(0); __builtin_amdgcn_s_setprio(1); } while (0)
#define CL_POST do { __builtin_amdgcn_s_setprio(0); __builtin_amdgcn_sched_barrier(0); } while (0)

    floatx4 acc[8][4] = {};
    bf16x8 af[4][2], bf[4][2];
    const int nt = K >> 6;

    // prologue: tile0 halves 0..3, tile1 half 0; wait tile0 complete
    STAGE(0, 0, 0); STAGE(0, 0, 1); STAGE(0, 0, 2); STAGE(0, 0, 3);
    STAGE(1, 1, 0);
    asm volatile("s_waitcnt vmcnt(2)" ::: "memory");
    PHASE_BAR;

    for (int kt = 0; kt < nt; ++kt) {
        const int cb = kt & 1;
        const unsigned short* Al = lds + cb * 32768;
        const unsigned short* Bl = lds + cb * 32768 + 16384;

        // ---- P0: read af(m-half0) + bf(all); stage (kt+1) half1 ----
#pragma unroll
        for (int mi = 0; mi < 4; ++mi)
#pragma unroll
            for (int ks = 0; ks < 2; ++ks) {
                int p = (wr*128 + mi*16 + l16) * 128 + ks*64 + quad*16;
                af[mi][ks] = *(const bf16x8*)((const char*)Al + SWZ(p));
            }
#pragma unroll
        for (int nj = 0; nj < 4; ++nj)
#pragma unroll
            for (int ks = 0; ks < 2; ++ks) {
                int p = (wc*64 + nj*16 + l16) * 128 + ks*64 + quad*16;
                bf[nj][ks] = *(const bf16x8*)((const char*)Bl + SWZ(p));
            }
        if (kt + 1 < nt) STAGE((kt + 1) & 1, kt + 1, 1);
        PHASE_BAR;
        CL_PRE;
#pragma unroll
        for (int mi = 0; mi < 4; ++mi)
#pragma unroll
            for (int nj = 0; nj < 2; ++nj)
#pragma unroll
                for (int ks = 0; ks < 2; ++ks)
                    acc[mi][nj] = __builtin_amdgcn_mfma_f32_16x16x32_bf16(af[mi][ks], bf[nj][ks], acc[mi][nj], 0, 0, 0);
        CL_POST;
        PHASE_BAR;

        // ---- P1: no reads; stage (kt+1) half2 ----
        if (kt + 1 < nt) STAGE((kt + 1) & 1, kt + 1, 2);
        PHASE_BAR;
        CL_PRE;
#pragma unroll
        for (int mi = 0; mi < 4; ++mi)
#pragma unroll
            for (int nj = 2; nj < 4; ++nj)
#pragma unroll
                for (int ks = 0; ks < 2; ++ks)
                    acc[mi][nj] = __builtin_amdgcn_mfma_f32_16x16x32_bf16(af[mi][ks], bf[nj][ks], acc[mi][nj], 0, 0, 0);
        CL_POST;
        PHASE_BAR;

        // ---- P2: read af(m-half1); stage (kt+1) half3 ----
#pragma unroll
        for (int mi = 0; mi < 4; ++mi)
#pragma unroll
            for (int ks = 0; ks < 2; ++ks) {
                int p = (wr*128 + 64 + mi*16 + l16) * 128 + ks*64 + quad*16;
                af[mi][ks] = *(const bf16x8*)((const char*)Al + SWZ(p));
            }
        if (kt + 1 < nt) STAGE((kt + 1) & 1, kt + 1, 3);
        PHASE_BAR;
        CL_PRE;
#pragma unroll
        for (int mi = 0; mi < 4; ++mi)
#pragma unroll
            for (int nj = 0; nj < 2; ++nj)
#pragma unroll
                for (int ks = 0; ks < 2; ++ks)
                    acc[4 + mi][nj] = __builtin_amdgcn_mfma_f32_16x16x32_bf16(af[mi][ks], bf[nj][ks], acc[4 + mi][nj], 0, 0, 0);
        CL_POST;
        PHASE_BAR;

        // ---- P3: no reads; stage (kt+2) half0 (into current buffer: B
        //      region fully consumed at P0, barrier-separated) ----
        if (kt + 2 < nt) STAGE(cb, kt + 2, 0);
        PHASE_BAR;
        CL_PRE;
#pragma unroll
        for (int mi = 0; mi < 4; ++mi)
#pragma unroll
            for (int nj = 2; nj < 4; ++nj)
#pragma unroll
                for (int ks = 0; ks < 2; ++ks)
                    acc[4 + mi][nj] = __builtin_amdgcn_mfma_f32_16x16x32_bf16(af[mi][ks], bf[nj][ks], acc[4 + mi][nj], 0, 0, 0);
        CL_POST;
        // tile boundary: counted wait — next tile's 4 halves must be in LDS;
        // leave (kt+2)'s half0 (2 loads) in flight.
        if (kt + 2 < nt)      { asm volatile("s_waitcnt vmcnt(2)" ::: "memory"); }
        else if (kt + 1 < nt) { asm volatile("s_waitcnt vmcnt(0)" ::: "memory"); }
        PHASE_BAR;
    }

    // epilogue: bias (+GELU) -> bf16
#pragma unroll
    for (int mi = 0; mi < 8; ++mi) {
#pragma unroll
        for (int nj = 0; nj < 4; ++nj) {
            const int col = bn + wc*64 + nj*16 + l16;
            const float bv = bias[col];
#pragma unroll
            for (int r = 0; r < 4; ++r) {
                const int row = bm + wr*128 + mi*16 + quad*4 + r;
                float v = acc[mi][nj][r] + bv;
                if (GELU) {
                    const float u = v;
                    float c = 2.302204225929898f * (u + 0.044715f * u * u * u);
                    c = fminf(c, 80.f);
                    const float e = exp2f(c);
                    v = u * (e / (1.0f + e));
                }
                outp[(size_t)row * N + col] = f2bf(v);
            }
        }
    }
#undef STAGE
#undef PHASE_BAR
#undef CL_PRE
#undef CL_POST
}

// set >64KB dynamic-LDS opt-in at .so load (outside graph capture)
static int g_big_lds_ok = 0;
struct Gemm256Init {
    Gemm256Init() {
        hipError_t e1 = hipFuncSetAttribute(reinterpret_cast<const void*>(gemm256<0>),
                                            hipFuncAttributeMaxDynamicSharedMemorySize, 131072);
        hipError_t e2 = hipFuncSetAttribute(reinterpret_cast<const void*>(gemm256<1>),
                                            hipFuncAttributeMaxDynamicSharedMemorySize, 131072);
        g_big_lds_ok = (e1 == hipSuccess && e2 == hipSuccess) ? 1 : 0;
    }
};
static Gemm256Init g_gemm256_init;

// ---------------------------------------------------------------------------
// split-K merge: outp[i] += part[i], fp32, float4-vectorized
// ---------------------------------------------------------------------------
__global__ __launch_bounds__(256)
void splitk_add(const float* __restrict__ part, float* __restrict__ outp)
{
    const size_t i = ((size_t)blockIdx.x * 256 + threadIdx.x) * 4;
    float4 a = *(const float4*)(outp + i);
    const float4 p = *(const float4*)(part + i);
    a.x += p.x; a.y += p.y; a.z += p.z; a.w += p.w;
    *(float4*)(outp + i) = a;
}

// ---------------------------------------------------------------------------
// split qkv -> q (scaled by QSCALE), k [B*H, L, 64] bf16 + present-K fp32
// ---------------------------------------------------------------------------
__global__ __launch_bounds__(256)
void split_qkv(const unsigned short* __restrict__ qkv,
               unsigned short* __restrict__ q, unsigned short* __restrict__ k,
               float* __restrict__ present)
{
    const size_t idx = (size_t)blockIdx.x * 256 + threadIdx.x; // [2 sel][32 bh][2048 l][8 grp]
    const int g8  = idx & 7;
    const int l   = (idx >> 3) & 2047;
    const int bh  = (idx >> 14) & 31;
    const int sel = (int)(idx >> 19);
    const int b = bh >> 4, h = bh & 15;
    const unsigned short* src = qkv + (size_t)(l * BATCH + b) * (3 * DIM) + sel * DIM + h * HDIM + g8 * 8;
    const uint4 val = *(const uint4*)src;
    const unsigned short* sv = (const unsigned short*)&val;
    if (sel == 0) {
        unsigned short ov[8];
#pragma unroll
        for (int j = 0; j < 8; ++j) ov[j] = f2bf(bf2f(sv[j]) * QSCALE);
        *(uint4*)(q + ((size_t)bh * L_SEQ + l) * HDIM + g8 * 8) = *(uint4*)ov;
    } else {
        *(uint4*)(k + ((size_t)bh * L_SEQ + l) * HDIM + g8 * 8) = val;
        float* p = present + (((size_t)b * NH + h) * L_SEQ + l) * HDIM + (size_t)g8 * 8;
        float4 f0, f1;
        f0.x = bf2f(sv[0]); f0.y = bf2f(sv[1]); f0.z = bf2f(sv[2]); f0.w = bf2f(sv[3]);
        f1.x = bf2f(sv[4]); f1.y = bf2f(sv[5]); f1.z = bf2f(sv[6]); f1.w = bf2f(sv[7]);
        ((float4*)p)[0] = f0; ((float4*)p)[1] = f1;
    }
}

// ---------------------------------------------------------------------------
// V transpose: qkv v-columns -> vt [bh][64 d][2048 l] bf16, + present-V fp32
// ---------------------------------------------------------------------------
__global__ __launch_bounds__(256)
void transpose_v(const unsigned short* __restrict__ qkv, unsigned short* __restrict__ vt,
                 float* __restrict__ present)
{
    __shared__ unsigned short tile[64][72];
    const int lt = blockIdx.x;            // 0..31
    const int bh = blockIdx.y;            // 0..31
    const int b = bh >> 4, h = bh & 15;
    const int t = threadIdx.x;
#pragma unroll
    for (int i = 0; i < 2; ++i) {
        const int idx = i * 256 + t;
        const int l = idx >> 3, c = (idx & 7) * 8;
        const uint4 val =
            *(const uint4*)(qkv + (size_t)((lt * 64 + l) * BATCH + b) * (3 * DIM) + 2 * DIM + h * HDIM + c);
        *(uint4*)(&tile[l][c]) = val;
        const unsigned short* sv = (const unsigned short*)&val;
        float* p = present + ((((size_t)BATCH + b) * NH + h) * L_SEQ + lt * 64 + l) * HDIM + c;
        float4 f0, f1;
        f0.x = bf2f(sv[0]); f0.y = bf2f(sv[1]); f0.z = bf2f(sv[2]); f0.w = bf2f(sv[3]);
        f1.x = bf2f(sv[4]); f1.y = bf2f(sv[5]); f1.z = bf2f(sv[6]); f1.w = bf2f(sv[7]);
        ((float4*)p)[0] = f0; ((float4*)p)[1] = f1;
    }
    __syncthreads();
#pragma unroll
    for (int i = 0; i < 2; ++i) {
        const int idx = i * 256 + t;
        const int d = idx >> 3, l0 = (idx & 7) * 8;
        const int kk = l0 >> 3;
        ushort4 o[2];
        unsigned short* ov = (unsigned short*)o;
#pragma unroll
        for (int jj = 0; jj < 8; ++jj) {
            const int j = (jj + kk) & 7;
            ov[j] = tile[l0 + j][d];
        }
        *(uint4*)(vt + ((size_t)bh * HDIM + d) * L_SEQ + lt * 64 + l0) = *(uint4*)o;
    }
}

// ---------------------------------------------------------------------------
// Flash attention, S^T + static-max softmax, KEY-SPLIT 2-way.
// ---------------------------------------------------------------------------
__global__ __launch_bounds__(256, 4)
void attn_kernel(const unsigned short* __restrict__ Q,
                 const unsigned short* __restrict__ Kk,
                 const unsigned short* __restrict__ Vt,
                 unsigned short* __restrict__ Opart,   // [2][4096][1024] bf16 unnormalized
                 float* __restrict__ Lpart)            // [2][32][2048] fp32
{
    const int qt = blockIdx.x;            // 0..15  (128 q rows each)
    const int ks = blockIdx.y;            // 0..1   (key split)
    const int bh = blockIdx.z;            // 0..31
    const int b = bh >> 4, h = bh & 15;
    const int t = threadIdx.x, w = t >> 6, lane = t & 63;
    const int quad = lane >> 4, l16 = lane & 15;

    __shared__ unsigned short Ks[64][72];      // [key][d]
    __shared__ unsigned short Vts[64][72];     // [d][key]
    __shared__ unsigned short Ps[4][32][72];   // per-wave P^T as [q][key]

    const size_t head_off = (size_t)bh * L_SEQ * HDIM;
    const int q_base = qt * 128 + w * 32;
    const int kt0 = ks * 1024;

    bf16x8 qf[2][2];
#pragma unroll
    for (int nf = 0; nf < 2; ++nf)
#pragma unroll
        for (int ds = 0; ds < 2; ++ds)
            qf[nf][ds] = *(const bf16x8*)(Q + head_off + (size_t)(q_base + nf*16 + l16) * HDIM + ds*32 + quad*8);

    const int sr = t >> 3;
    const int sc = (t & 7) * 8;

    floatx4 o[4][2] = {};              // O^T[d=dt*16+quad*4+r][q=nf*16+l16]
    float l_i[2] = {0.f, 0.f};

    for (int kt = kt0; kt < kt0 + 1024; kt += 64) {
        __syncthreads();
#pragma unroll
        for (int i = 0; i < 2; ++i) {
            const int row = sr + i * 32;
            *(uint4*)(&Ks[row][sc])  = *(const uint4*)(Kk + head_off + (size_t)(kt + row) * HDIM + sc);
            *(uint4*)(&Vts[row][sc]) = *(const uint4*)(Vt + head_off + (size_t)row * L_SEQ + kt + sc);
        }
        __syncthreads();

        floatx4 s[4][2] = {};
#pragma unroll
        for (int ds = 0; ds < 2; ++ds)
#pragma unroll
            for (int jt = 0; jt < 4; ++jt) {
                const bf16x8 kf = *(const bf16x8*)(&Ks[jt*16 + l16][ds*32 + quad*8]);
                s[jt][0] = __builtin_amdgcn_mfma_f32_16x16x32_bf16(kf, qf[0][ds], s[jt][0], 0, 0, 0);
                s[jt][1] = __builtin_amdgcn_mfma_f32_16x16x32_bf16(kf, qf[1][ds], s[jt][1], 0, 0, 0);
            }

#pragma unroll
        for (int nf = 0; nf < 2; ++nf)
#pragma unroll
            for (int jt = 0; jt < 4; ++jt) {
                const float p0 = exp2f(s[jt][nf][0]);
                const float p1 = exp2f(s[jt][nf][1]);
                const float p2 = exp2f(s[jt][nf][2]);
                const float p3 = exp2f(s[jt][nf][3]);
                l_i[nf] += (p0 + p1) + (p2 + p3);
                uint2 pk;
                pk.x = __builtin_amdgcn_perm(fbits(p1), fbits(p0), 0x07060302u);
                pk.y = __builtin_amdgcn_perm(fbits(p3), fbits(p2), 0x07060302u);
                *(uint2*)(&Ps[w][nf*16 + l16][jt*16 + quad*4]) = pk;
            }

#pragma unroll
        for (int kk = 0; kk < 2; ++kk) {
            const bf16x8 pf0 = *(const bf16x8*)(&Ps[w][l16]     [kk*32 + quad*8]);
            const bf16x8 pf1 = *(const bf16x8*)(&Ps[w][16 + l16][kk*32 + quad*8]);
#pragma unroll
            for (int dt = 0; dt < 4; ++dt) {
                const bf16x8 vf = *(const bf16x8*)(&Vts[dt*16 + l16][kk*32 + quad*8]);
                o[dt][0] = __builtin_amdgcn_mfma_f32_16x16x32_bf16(vf, pf0, o[dt][0], 0, 0, 0);
                o[dt][1] = __builtin_amdgcn_mfma_f32_16x16x32_bf16(vf, pf1, o[dt][1], 0, 0, 0);
            }
        }
    }

    unsigned short* Op = Opart + (size_t)ks * ROWS * DIM;
#pragma unroll
    for (int nf = 0; nf < 2; ++nf) {
        float l = l_i[nf];
        l += __shfl_xor(l, 16, 64);
        l += __shfl_xor(l, 32, 64);
        const int q = q_base + nf*16 + l16;
        if (quad == 0)
            Lpart[((size_t)ks * 32 + bh) * L_SEQ + q] = l;
#pragma unroll
        for (int dt = 0; dt < 4; ++dt) {
            ushort4 ov;
            ov.x = f2bf(o[dt][nf][0]); ov.y = f2bf(o[dt][nf][1]);
            ov.z = f2bf(o[dt][nf][2]); ov.w = f2bf(o[dt][nf][3]);
            *(ushort4*)(Op + (size_t)(q * BATCH + b) * DIM + h * HDIM + dt*16 + quad*4) = ov;
        }
    }
}

// ---------------------------------------------------------------------------
// Merge: aw[row][col] = (O0+O1) / (l0+l1), bf16. One block per row.
// ---------------------------------------------------------------------------
__global__ __launch_bounds__(256)
void attn_merge(const unsigned short* __restrict__ Opart,
                const float* __restrict__ Lpart,
                unsigned short* __restrict__ Aout)
{
    const int row = blockIdx.x;           // 0..4095 (= q*BATCH + b)
    const int q = row >> 1, b = row & 1;
    const int t = threadIdx.x;
    const int col = t * 4;
    const int h = col >> 6;
    const int bh = b * 16 + h;
    const float l0 = Lpart[(size_t)bh * L_SEQ + q];
    const float l1 = Lpart[((size_t)32 + bh) * L_SEQ + q];
    const float inv = 1.0f / (l0 + l1);
    const ushort4 o0 = *(const ushort4*)(Opart + (size_t)row * DIM + col);
    const ushort4 o1 = *(const ushort4*)(Opart + (size_t)ROWS * DIM + (size_t)row * DIM + col);
    ushort4 ov;
    ov.x = f2bf((bf2f(o0.x) + bf2f(o1.x)) * inv);
    ov.y = f2bf((bf2f(o0.y) + bf2f(o1.y)) * inv);
    ov.z = f2bf((bf2f(o0.z) + bf2f(o1.z)) * inv);
    ov.w = f2bf((bf2f(o0.w) + bf2f(o1.w)) * inv);
    *(ushort4*)(Aout + (size_t)row * DIM + col) = ov;
}

// ---------------------------------------------------------------------------
// Launch
// ---------------------------------------------------------------------------
extern "C" void kernel_launch(void* const* d_in, const int* in_sizes, int n_in,
                              void* d_out, int out_size, void* d_ws, size_t ws_size,
                              hipStream_t stream)
{
    const float* x      = (const float*)d_in[0];
    const float* ln1_g  = (const float*)d_in[1];
    const float* ln1_b  = (const float*)d_in[2];
    const float* w_attn = (const float*)d_in[3];
    const float* b_attn = (const float*)d_in[4];
    const float* w_proj = (const float*)d_in[5];
    const float* b_proj = (const float*)d_in[6];
    const float* ln2_g  = (const float*)d_in[7];
    const float* ln2_b  = (const float*)d_in[8];
    const float* w_fc   = (const float*)d_in[9];
    const float* b_fc   = (const float*)d_in[10];
    const float* w_out  = (const float*)d_in[11];
    const float* b_out  = (const float*)d_in[12];

    char* ws = (char*)d_ws;
    unsigned short* watT   = (unsigned short*)(ws + 0);           // [3072,1024] bf16
    unsigned short* wprojT = (unsigned short*)(ws + 6291456);     // [1024,1024]
    unsigned short* wfcT   = (unsigned short*)(ws + 8388608);     // [4096,1024]
    unsigned short* woutT  = (unsigned short*)(ws + 16777216);    // [1024,4096]
    unsigned short* h      = (unsigned short*)(ws + 25165824);    // [4096,1024]
    unsigned short* qkv    = (unsigned short*)(ws + 33554432);    // [4096,3072]
    // After split/transpose_v, qkv region is dead -> reuse for attn partials:
    unsigned short* opart  = (unsigned short*)(ws + 33554432);    // [2][4096][1024] bf16 (16MB)
    float*          lpart  = (float*)(ws + 50331648);             // [2][32][2048] fp32 (512KB)
    unsigned short* mws    = (unsigned short*)(ws + 33554432);    // [4096,4096] (reuses region later)
    unsigned short* qw     = (unsigned short*)(ws + 58720256);    // [32,2048,64]
    unsigned short* kw     = (unsigned short*)(ws + 67108864);    // [32,2048,64]
    unsigned short* vt     = (unsigned short*)(ws + 75497472);    // [32,64,2048] (transposed V)
    unsigned short* aw     = (unsigned short*)(ws + 83886080);    // [4096,1024]
    unsigned short* x2     = (unsigned short*)(ws + 92274688);    // [4096,1024] bf16 residual stream
    // split-K partial for the out GEMM: 16MB fp32, reuses vt+aw (dead at step 9)
    float*          kpart  = (float*)(ws + 75497472);             // [4096,1024] fp32

    float* xout    = (float*)d_out;                // [2048,2,1024]
    float* present = (float*)d_out + 4194304;      // [2,2,16,2048,64]

    // 1. all weight transposes (fp32 -> bf16 [N,K])
    transpose_all<<<12288, 256, 0, stream>>>(w_attn, watT, w_proj, wprojT, w_fc, wfcT, w_out, woutT);

    // 2. LN1
    ln_rows<0><<<ROWS, 256, 0, stream>>>(x, ln1_g, ln1_b, h);
    // 3. QKV GEMM -> bf16 (256^2 8-phase; fallback to m97 structure if no big LDS)
    if (g_big_lds_ok)
        gemm256<0><<<dim3(192), 512, 131072, stream>>>(h, watT, b_attn, qkv, ROWS, 3*DIM, DIM, 16);
    else
        gemm_bt<0,0,1,4,1><<<dim3(32, 24), 256, 0, stream>>>(h, watT, b_attn, nullptr, qkv, nullptr, ROWS, 3*DIM, DIM);
    // 4. split (q scaled, k, present-K) + V transpose (+present-V)
    split_qkv<<<4096, 256, 0, stream>>>(qkv, qw, kw, present);
    transpose_v<<<dim3(32, 32), 256, 0, stream>>>(qkv, vt, present);
    // 5. attention (key-split x2 -> 1024 blocks, 4/CU) + merge
    attn_kernel<<<dim3(16, 2, 32), 256, 0, stream>>>(qw, kw, vt, opart, lpart);
    attn_merge<<<ROWS, 256, 0, stream>>>(opart, lpart, aw);
    // 6. proj + residual -> x2 bf16 (64x128 tiles: 512 blocks)
    gemm_bt<0,1,1,2,1><<<dim3(64, 8), 256, 0, stream>>>(aw, wprojT, b_proj, x, x2, nullptr, ROWS, DIM, DIM);
    // 7. LN2 (bf16 input)
    ln_rows<1><<<ROWS, 256, 0, stream>>>(x2, ln2_g, ln2_b, h);
    // 8. FC + GELU -> bf16 (256^2 8-phase)
    if (g_big_lds_ok)
        gemm256<1><<<dim3(256), 512, 131072, stream>>>(h, wfcT, b_fc, mws, ROWS, DFF_, DIM, 16);
    else
        gemm_bt<1,0,1,4,1><<<dim3(32, 32), 256, 0, stream>>>(h, wfcT, b_fc, nullptr, mws, nullptr, ROWS, DFF_, DIM);
    // 9. out GEMM, 128x128 tile + split-K 2 (grid 32x8x2 = 512 blocks, 2/CU)
    gemm_bt<0,2,0,4,2><<<dim3(32, 8, 2), 256, 0, stream>>>(mws, woutT, b_out, x2, xout, kpart, ROWS, DIM, DFF_);
    splitk_add<<<4096, 256, 0, stream>>>(kpart, xout);
}

// Round 3
// 412.814 us; speedup vs baseline: 1.0447x; 1.0447x over previous
//
#include <hip/hip_runtime.h>
#include <stdint.h>

// Problem constants
#define L_SEQ 2048
#define BATCH 2
#define DIM   1024
#define NH    16
#define HDIM  64
#define DFF_  4096
#define ROWS  (L_SEQ*BATCH)   // 4096 token rows, row index = l*BATCH + b

// softmax scale folded into Q at split time: (1/sqrt(64)) * log2(e)
#define QSCALE 0.18033688011112042f

typedef __attribute__((ext_vector_type(8))) short  bf16x8;
typedef __attribute__((ext_vector_type(4))) float  floatx4;

__device__ __forceinline__ unsigned short f2bf(float f) {
    union { float f; uint32_t u; } x; x.f = f;
    uint32_t r = x.u + 0x7fffu + ((x.u >> 16) & 1u);   // RNE
    return (unsigned short)(r >> 16);
}
__device__ __forceinline__ float bf2f(unsigned short b) {
    union { uint32_t u; float f; } x; x.u = ((uint32_t)b) << 16;
    return x.f;
}
__device__ __forceinline__ uint32_t fbits(float f) {
    union { float f; uint32_t u; } x; x.f = f; return x.u;
}

// async global->LDS, 16B per lane; lds dest = wave-uniform base + lane*16
__device__ __forceinline__ void load_lds16(const unsigned short* g, unsigned short* l) {
    __builtin_amdgcn_global_load_lds(
        (const __attribute__((address_space(1))) unsigned int*)g,
        (__attribute__((address_space(3))) unsigned int*)l, 16, 0, 0);
}

// ---------------------------------------------------------------------------
// All 4 weight transposes in one kernel: fp32 [K,N] -> bf16 [N,K], 32x32 tiles
// ---------------------------------------------------------------------------
__global__ __launch_bounds__(256)
void transpose_all(const float* __restrict__ s0, unsigned short* __restrict__ d0,
                   const float* __restrict__ s1, unsigned short* __restrict__ d1,
                   const float* __restrict__ s2, unsigned short* __restrict__ d2,
                   const float* __restrict__ s3, unsigned short* __restrict__ d3)
{
    const int id = blockIdx.x;
    const float* src; unsigned short* dst; int K, N, local;
    if (id < 3072)      { src = s0; dst = d0; K = 1024; N = 3072; local = id; }
    else if (id < 4096) { src = s1; dst = d1; K = 1024; N = 1024; local = id - 3072; }
    else if (id < 8192) { src = s2; dst = d2; K = 1024; N = 4096; local = id - 4096; }
    else                { src = s3; dst = d3; K = 4096; N = 1024; local = id - 8192; }
    const int nN = N >> 5;
    const int bk = (local / nN) * 32, bn = (local % nN) * 32;

    __shared__ float tile[32][36];
    const int t = threadIdx.x;
    const int r = t >> 3, c4 = (t & 7) * 4;
    *(float4*)&tile[r][c4] = *(const float4*)(src + (size_t)(bk + r) * N + bn + c4);
    __syncthreads();
    ushort4 o;
    o.x = f2bf(tile[c4 + 0][r]);
    o.y = f2bf(tile[c4 + 1][r]);
    o.z = f2bf(tile[c4 + 2][r]);
    o.w = f2bf(tile[c4 + 3][r]);
    *(ushort4*)(dst + (size_t)(bn + r) * K + bk + c4) = o;
}

// ---------------------------------------------------------------------------
// LayerNorm: [4096,1024] fp32 or bf16 input -> bf16 out, one block per row
// ---------------------------------------------------------------------------
template<int INBF16>
__global__ __launch_bounds__(256)
void ln_rows(const void* __restrict__ xin, const float* __restrict__ g,
             const float* __restrict__ bta, unsigned short* __restrict__ out)
{
    const int row = blockIdx.x;
    const int t = threadIdx.x;
    float4 v;
    if (INBF16) {
        const ushort4 u = ((const ushort4*)((const unsigned short*)xin + (size_t)row * DIM))[t];
        v.x = bf2f(u.x); v.y = bf2f(u.y); v.z = bf2f(u.z); v.w = bf2f(u.w);
    } else {
        v = ((const float4*)((const float*)xin + (size_t)row * DIM))[t];
    }
    float s  = v.x + v.y + v.z + v.w;
    float s2 = v.x*v.x + v.y*v.y + v.z*v.z + v.w*v.w;
#pragma unroll
    for (int d = 1; d < 64; d <<= 1) { s += __shfl_xor(s, d, 64); s2 += __shfl_xor(s2, d, 64); }
    __shared__ float ss[4], ss2[4];
    const int w = t >> 6, lane = t & 63;
    if (lane == 0) { ss[w] = s; ss2[w] = s2; }
    __syncthreads();
    s  = ss[0] + ss[1] + ss[2] + ss[3];
    s2 = ss2[0] + ss2[1] + ss2[2] + ss2[3];
    const float mu   = s * (1.0f / DIM);
    const float var  = s2 * (1.0f / DIM) - mu * mu;
    const float rstd = rsqrtf(var + 1e-5f);
    const float4 gv = ((const float4*)g)[t];
    const float4 bv = ((const float4*)bta)[t];
    ushort4 o;
    o.x = f2bf((v.x - mu) * rstd * gv.x + bv.x);
    o.y = f2bf((v.y - mu) * rstd * gv.y + bv.y);
    o.z = f2bf((v.z - mu) * rstd * gv.z + bv.z);
    o.w = f2bf((v.w - mu) * rstd * gv.w + bv.w);
    *(ushort4*)(out + (size_t)row * DIM + t * 4) = o;
}

// ---------------------------------------------------------------------------
// bf16 GEMM, B^T input (Bt [N,K]); C = A@B + bias (+resid) (gelu?)
// MI=4: 128x128 tile; MI=2: 64x128 tile. BK=32, m97 structure.
// RESID: 0=none, 1=fp32, 2=bf16
// SPLITK>1: blockIdx.z = K-slice; kz>0 writes raw fp32 partial.
// ---------------------------------------------------------------------------
template<int GELU, int RESID, int OUTBF16, int MI, int SPLITK>
__global__ __launch_bounds__(256)
void gemm_bt(const unsigned short* __restrict__ A,   // [M,K] bf16
             const unsigned short* __restrict__ Bt,  // [N,K] bf16
             const float* __restrict__ bias,         // [N]
             const void* __restrict__ resid,         // [M,N] fp32/bf16 or null
             void* __restrict__ outp,                // bf16 or fp32 [M,N]
             float* __restrict__ part,               // fp32 partials (SPLITK>1)
             int M, int N, int K)
{
    __shared__ unsigned short As[MI * 32 * 32];   // flat, unpadded
    __shared__ unsigned short Bs[128 * 32];
    const int t = threadIdx.x;
    const int w = t >> 6, lane = t & 63;
    const int quad = lane >> 4, l16 = lane & 15;
    const int wm = (w >> 1) * (MI * 16), wn = (w & 1) * 64;
    const int bm = blockIdx.x * (MI * 32), bn = blockIdx.y * 128;

    const int srow = lane >> 2;
    const int scol = (lane & 3) * 8;

    const unsigned short* Ab = A  + (size_t)bm * K;
    const unsigned short* Bb = Bt + (size_t)bn * K;

    floatx4 acc[MI][4] = {};

    const int kspan = (SPLITK > 1) ? (K / SPLITK) : K;
    const int k0    = (SPLITK > 1) ? blockIdx.z * kspan : 0;

    for (int kc = k0; kc < k0 + kspan; kc += 32) {
        __syncthreads();
#pragma unroll
        for (int i = 0; i < MI / 2; ++i) {
            const int r0 = (i * 4 + w) * 16;
            load_lds16(Ab + (size_t)(r0 + srow) * K + kc + scol, As + r0 * 32);
        }
#pragma unroll
        for (int i = 0; i < 2; ++i) {
            const int r0 = (i * 4 + w) * 16;
            load_lds16(Bb + (size_t)(r0 + srow) * K + kc + scol, Bs + r0 * 32);
        }
        __syncthreads();
        bf16x8 af[MI], bf[4];
#pragma unroll
        for (int i = 0; i < MI; ++i) af[i] = *(const bf16x8*)(As + (wm + i*16 + l16) * 32 + quad * 8);
#pragma unroll
        for (int j = 0; j < 4; ++j) bf[j] = *(const bf16x8*)(Bs + (wn + j*16 + l16) * 32 + quad * 8);
#pragma unroll
        for (int i = 0; i < MI; ++i)
#pragma unroll
            for (int j = 0; j < 4; ++j)
                acc[i][j] = __builtin_amdgcn_mfma_f32_16x16x32_bf16(af[i], bf[j], acc[i][j], 0, 0, 0);
    }

    if (SPLITK > 1 && blockIdx.z > 0) {
        float* po = part + (size_t)(blockIdx.z - 1) * ((size_t)M * N);
#pragma unroll
        for (int i = 0; i < MI; ++i)
#pragma unroll
            for (int j = 0; j < 4; ++j) {
                const int col = bn + wn + j*16 + l16;
#pragma unroll
                for (int r = 0; r < 4; ++r) {
                    const int row = bm + wm + i*16 + quad*4 + r;
                    po[(size_t)row * N + col] = acc[i][j][r];
                }
            }
        return;
    }

#pragma unroll
    for (int i = 0; i < MI; ++i) {
#pragma unroll
        for (int j = 0; j < 4; ++j) {
            const int col = bn + wn + j*16 + l16;
            const float bv = bias[col];
#pragma unroll
            for (int r = 0; r < 4; ++r) {
                const int row = bm + wm + i*16 + quad*4 + r;
                float v = acc[i][j][r] + bv;
                if (RESID == 1) v += ((const float*)resid)[(size_t)row * N + col];
                if (RESID == 2) v += bf2f(((const unsigned short*)resid)[(size_t)row * N + col]);
                if (GELU) {
                    const float u = v;
                    float c = 2.302204225929898f * (u + 0.044715f * u * u * u);
                    c = fminf(c, 80.f);
                    const float e = exp2f(c);
                    v = u * (e / (1.0f + e));
                }
                if (OUTBF16) ((unsigned short*)outp)[(size_t)row * N + col] = f2bf(v);
                else         ((float*)outp)[(size_t)row * N + col] = v;
            }
        }
    }
}

// ---------------------------------------------------------------------------
// 256x256-tile deep-pipelined GEMM, BK=32, 64 KiB STATIC LDS.
// 512 threads = 8 waves (2 M x 4 N), per-wave 128x64 output, acc[8][4].
// LDS: 2 buffers x (A[256][32] 16KB + B[256][32] 16KB), XOR-swizzled
//   (byte ^= ((byte>>7)&3)<<4 within each 16KB operand region) -> 2-way
//   bank aliasing on ds_read_b128 (free, m136). Staged via global_load_lds
//   with linear LDS dest + pre-swizzled global source (rule #21).
// Per K-tile i (2 phases x 16 MFMA):
//   P0: ds_read af[0..3]+bf[0..3](buf i&1); STAGE A(i+1)->buf (i+1)&1
//   P1: ds_read af-hi(buf i&1);             STAGE B(i+2)->buf i&1 (B region
//       freed at P0); end-of-tile s_waitcnt vmcnt(2) leaves B(i+2) in flight.
// Latency budgets: A(i+1) ~2 phases, B(i+2) ~4 phases. Branchless clamped
// tail (redundant in-bounds re-stages of the last tile, never read).
// Requires M%256==0, N%256==0, K/SPLITK % 64 == 0, gridDim.x % 8 == 0.
// ---------------------------------------------------------------------------
#define SWZ32(p) ((p) ^ ((((p) >> 7) & 3) << 4))

template<int GELU, int RESID, int OUTBF16, int SPLITK>
__global__ __launch_bounds__(512, 2)
void gemm256b(const unsigned short* __restrict__ A,   // [M,K] bf16
              const unsigned short* __restrict__ Bt,  // [N,K] bf16
              const float* __restrict__ bias,         // [N]
              const void* __restrict__ resid,         // [M,N] or null
              void* __restrict__ outp,                // bf16 or fp32 [M,N]
              float* __restrict__ part,               // fp32 partials
              int M, int N, int K, int nbx)
{
    __shared__ unsigned short lds[32768];            // 64 KiB exactly
    const int t = threadIdx.x;
    const int w = t >> 6, lane = t & 63;
    const int quad = lane >> 4, l16 = lane & 15;
    const int wr = w >> 2, wc = w & 3;

    // bijective XCD swizzle (gridDim.x % 8 == 0)
    const int nwg = gridDim.x;
    const int cpx = nwg >> 3;
    const int bid = (blockIdx.x & 7) * cpx + (blockIdx.x >> 3);
    const int bm = (bid % nbx) * 256, bn = (bid / nbx) * 256;

    const unsigned short* Ab = A  + (size_t)bm * K;
    const unsigned short* Bb = Bt + (size_t)bn * K;

    // pre-swizzled staging source offsets (elements); LDS dest is linear
    const int q0 = t * 16, q1 = 8192 + t * 16;       // bytes within 16KB region
    const int s0 = SWZ32(q0), s1 = SWZ32(q1);
    const size_t aoff0 = (size_t)(s0 >> 6) * K + ((s0 & 63) >> 1);
    const size_t aoff1 = (size_t)(s1 >> 6) * K + ((s1 & 63) >> 1);

    // dstE_ in elements: A region of buf b = b*16384, B region = b*16384+8192
#define STG(dstE_, src_, kta_) do {                                        \
        const unsigned short* g_ = (src_) + (size_t)(kta_) * 32;           \
        load_lds16(g_ + aoff0, lds + (dstE_) + w * 512);                   \
        load_lds16(g_ + aoff1, lds + (dstE_) + 4096 + w * 512);            \
    } while (0)
#define BARF    do { __builtin_amdgcn_s_barrier(); asm volatile("" ::: "memory"); } while (0)
#define CL_PRE  do { asm volatile("s_waitcnt lgkmcnt(0)" ::: "memory");    \
                     __builtin_amdgcn_sched_barrier(0);                    \
                     __builtin_amdgcn_s_setprio(1); } while (0)
#define CL_POST do { __builtin_amdgcn_s_setprio(0);                        \
                     __builtin_amdgcn_sched_barrier(0); } while (0)

    floatx4 acc[8][4] = {};
    const int nt  = ((SPLITK > 1) ? (K / SPLITK) : K) >> 5;
    const int ktb = (SPLITK > 1) ? blockIdx.y * nt : 0;

    // prologue: tile0 A+B -> buf0; tile1 B -> buf1; wait tile0 complete
    STG(0,            Ab, ktb);
    STG(8192,         Bb, ktb);
    STG(16384 + 8192, Bb, ktb + 1);
    asm volatile("s_waitcnt vmcnt(2)" ::: "memory");
    BARF;

    for (int i = 0; i < nt; ++i) {
        const int cb = i & 1;
        const int i1 = (i + 1 < nt) ? i + 1 : nt - 1;
        const int i2 = (i + 2 < nt) ? i + 2 : nt - 1;
        const char* Abase = (const char*)lds + cb * 32768;
        const char* Bbase = Abase + 16384;
        bf16x8 af[4], bf[4];

        // ---- P0: read A-lo + B(all); stage A(i+1) -> other buffer ----
        STG((cb ^ 1) * 16384, Ab, ktb + i1);
#pragma unroll
        for (int mi = 0; mi < 4; ++mi) {
            const int p = (wr * 128 + mi * 16 + l16) * 64 + quad * 16;
            af[mi] = *(const bf16x8*)(Abase + SWZ32(p));
        }
#pragma unroll
        for (int nj = 0; nj < 4; ++nj) {
            const int p = (wc * 64 + nj * 16 + l16) * 64 + quad * 16;
            bf[nj] = *(const bf16x8*)(Bbase + SWZ32(p));
        }
        BARF;
        CL_PRE;
#pragma unroll
        for (int mi = 0; mi < 4; ++mi)
#pragma unroll
            for (int nj = 0; nj < 4; ++nj)
                acc[mi][nj] = __builtin_amdgcn_mfma_f32_16x16x32_bf16(af[mi], bf[nj], acc[mi][nj], 0, 0, 0);
        CL_POST;
        BARF;

        // ---- P1: read A-hi; stage B(i+2) -> current buffer (B freed @P0) ----
        STG(cb * 16384 + 8192, Bb, ktb + i2);
#pragma unroll
        for (int mi = 0; mi < 4; ++mi) {
            const int p = (wr * 128 + 64 + mi * 16 + l16) * 64 + quad * 16;
            af[mi] = *(const bf16x8*)(Abase + SWZ32(p));
        }
        BARF;
        CL_PRE;
#pragma unroll
        for (int mi = 0; mi < 4; ++mi)
#pragma unroll
            for (int nj = 0; nj < 4; ++nj)
                acc[4 + mi][nj] = __builtin_amdgcn_mfma_f32_16x16x32_bf16(af[mi], bf[nj], acc[4 + mi][nj], 0, 0, 0);
        CL_POST;
        // tile boundary: A(i+1) must be resident; leave B(i+2) in flight.
        asm volatile("s_waitcnt vmcnt(2)" ::: "memory");
        BARF;
    }

    if (SPLITK > 1 && blockIdx.y > 0) {
        float* po = part + (size_t)(blockIdx.y - 1) * ((size_t)M * N);
#pragma unroll
        for (int mi = 0; mi < 8; ++mi)
#pragma unroll
            for (int nj = 0; nj < 4; ++nj) {
                const int col = bn + wc * 64 + nj * 16 + l16;
#pragma unroll
                for (int r = 0; r < 4; ++r) {
                    const int row = bm + wr * 128 + mi * 16 + quad * 4 + r;
                    po[(size_t)row * N + col] = acc[mi][nj][r];
                }
            }
        return;
    }

#pragma unroll
    for (int mi = 0; mi < 8; ++mi) {
#pragma unroll
        for (int nj = 0; nj < 4; ++nj) {
            const int col = bn + wc * 64 + nj * 16 + l16;
            const float bv = bias[col];
#pragma unroll
            for (int r = 0; r < 4; ++r) {
                const int row = bm + wr * 128 + mi * 16 + quad * 4 + r;
                float v = acc[mi][nj][r] + bv;
                if (RESID == 1) v += ((const float*)resid)[(size_t)row * N + col];
                if (RESID == 2) v += bf2f(((const unsigned short*)resid)[(size_t)row * N + col]);
                if (GELU) {
                    const float u = v;
                    float c = 2.302204225929898f * (u + 0.044715f * u * u * u);
                    c = fminf(c, 80.f);
                    const float e = exp2f(c);
                    v = u * (e / (1.0f + e));
                }
                if (OUTBF16) ((unsigned short*)outp)[(size_t)row * N + col] = f2bf(v);
                else         ((float*)outp)[(size_t)row * N + col] = v;
            }
        }
    }
#undef STG
#undef BARF
#undef CL_PRE
#undef CL_POST
}

// ---------------------------------------------------------------------------
// split-K merge: outp[i] += part[i], fp32, float4-vectorized
// ---------------------------------------------------------------------------
__global__ __launch_bounds__(256)
void splitk_add(const float* __restrict__ part, float* __restrict__ outp)
{
    const size_t i = ((size_t)blockIdx.x * 256 + threadIdx.x) * 4;
    float4 a = *(const float4*)(outp + i);
    const float4 p = *(const float4*)(part + i);
    a.x += p.x; a.y += p.y; a.z += p.z; a.w += p.w;
    *(float4*)(outp + i) = a;
}

// ---------------------------------------------------------------------------
// split qkv -> q (scaled by QSCALE), k [B*H, L, 64] bf16 + present-K fp32
// ---------------------------------------------------------------------------
__global__ __launch_bounds__(256)
void split_qkv(const unsigned short* __restrict__ qkv,
               unsigned short* __restrict__ q, unsigned short* __restrict__ k,
               float* __restrict__ present)
{
    const size_t idx = (size_t)blockIdx.x * 256 + threadIdx.x; // [2 sel][32 bh][2048 l][8 grp]
    const int g8  = idx & 7;
    const int l   = (idx >> 3) & 2047;
    const int bh  = (idx >> 14) & 31;
    const int sel = (int)(idx >> 19);
    const int b = bh >> 4, h = bh & 15;
    const unsigned short* src = qkv + (size_t)(l * BATCH + b) * (3 * DIM) + sel * DIM + h * HDIM + g8 * 8;
    const uint4 val = *(const uint4*)src;
    const unsigned short* sv = (const unsigned short*)&val;
    if (sel == 0) {
        unsigned short ov[8];
#pragma unroll
        for (int j = 0; j < 8; ++j) ov[j] = f2bf(bf2f(sv[j]) * QSCALE);
        *(uint4*)(q + ((size_t)bh * L_SEQ + l) * HDIM + g8 * 8) = *(uint4*)ov;
    } else {
        *(uint4*)(k + ((size_t)bh * L_SEQ + l) * HDIM + g8 * 8) = val;
        float* p = present + (((size_t)b * NH + h) * L_SEQ + l) * HDIM + (size_t)g8 * 8;
        float4 f0, f1;
        f0.x = bf2f(sv[0]); f0.y = bf2f(sv[1]); f0.z = bf2f(sv[2]); f0.w = bf2f(sv[3]);
        f1.x = bf2f(sv[4]); f1.y = bf2f(sv[5]); f1.z = bf2f(sv[6]); f1.w = bf2f(sv[7]);
        ((float4*)p)[0] = f0; ((float4*)p)[1] = f1;
    }
}

// ---------------------------------------------------------------------------
// V transpose: qkv v-columns -> vt [bh][64 d][2048 l] bf16, + present-V fp32
// ---------------------------------------------------------------------------
__global__ __launch_bounds__(256)
void transpose_v(const unsigned short* __restrict__ qkv, unsigned short* __restrict__ vt,
                 float* __restrict__ present)
{
    __shared__ unsigned short tile[64][72];
    const int lt = blockIdx.x;            // 0..31
    const int bh = blockIdx.y;            // 0..31
    const int b = bh >> 4, h = bh & 15;
    const int t = threadIdx.x;
#pragma unroll
    for (int i = 0; i < 2; ++i) {
        const int idx = i * 256 + t;
        const int l = idx >> 3, c = (idx & 7) * 8;
        const uint4 val =
            *(const uint4*)(qkv + (size_t)((lt * 64 + l) * BATCH + b) * (3 * DIM) + 2 * DIM + h * HDIM + c);
        *(uint4*)(&tile[l][c]) = val;
        const unsigned short* sv = (const unsigned short*)&val;
        float* p = present + ((((size_t)BATCH + b) * NH + h) * L_SEQ + lt * 64 + l) * HDIM + c;
        float4 f0, f1;
        f0.x = bf2f(sv[0]); f0.y = bf2f(sv[1]); f0.z = bf2f(sv[2]); f0.w = bf2f(sv[3]);
        f1.x = bf2f(sv[4]); f1.y = bf2f(sv[5]); f1.z = bf2f(sv[6]); f1.w = bf2f(sv[7]);
        ((float4*)p)[0] = f0; ((float4*)p)[1] = f1;
    }
    __syncthreads();
#pragma unroll
    for (int i = 0; i < 2; ++i) {
        const int idx = i * 256 + t;
        const int d = idx >> 3, l0 = (idx & 7) * 8;
        const int kk = l0 >> 3;
        ushort4 o[2];
        unsigned short* ov = (unsigned short*)o;
#pragma unroll
        for (int jj = 0; jj < 8; ++jj) {
            const int j = (jj + kk) & 7;
            ov[j] = tile[l0 + j][d];
        }
        *(uint4*)(vt + ((size_t)bh * HDIM + d) * L_SEQ + lt * 64 + l0) = *(uint4*)o;
    }
}

// ---------------------------------------------------------------------------
// Flash attention, S^T + static-max softmax, KEY-SPLIT 2-way.
// ---------------------------------------------------------------------------
__global__ __launch_bounds__(256, 4)
void attn_kernel(const unsigned short* __restrict__ Q,
                 const unsigned short* __restrict__ Kk,
                 const unsigned short* __restrict__ Vt,
                 unsigned short* __restrict__ Opart,   // [2][4096][1024] bf16 unnormalized
                 float* __restrict__ Lpart)            // [2][32][2048] fp32
{
    const int qt = blockIdx.x;            // 0..15  (128 q rows each)
    const int ks = blockIdx.y;            // 0..1   (key split)
    const int bh = blockIdx.z;            // 0..31
    const int b = bh >> 4, h = bh & 15;
    const int t = threadIdx.x, w = t >> 6, lane = t & 63;
    const int quad = lane >> 4, l16 = lane & 15;

    __shared__ unsigned short Ks[64][72];      // [key][d]
    __shared__ unsigned short Vts[64][72];     // [d][key]
    __shared__ unsigned short Ps[4][32][72];   // per-wave P^T as [q][key]

    const size_t head_off = (size_t)bh * L_SEQ * HDIM;
    const int q_base = qt * 128 + w * 32;
    const int kt0 = ks * 1024;

    bf16x8 qf[2][2];
#pragma unroll
    for (int nf = 0; nf < 2; ++nf)
#pragma unroll
        for (int ds = 0; ds < 2; ++ds)
            qf[nf][ds] = *(const bf16x8*)(Q + head_off + (size_t)(q_base + nf*16 + l16) * HDIM + ds*32 + quad*8);

    const int sr = t >> 3;
    const int sc = (t & 7) * 8;

    floatx4 o[4][2] = {};              // O^T[d=dt*16+quad*4+r][q=nf*16+l16]
    float l_i[2] = {0.f, 0.f};

    for (int kt = kt0; kt < kt0 + 1024; kt += 64) {
        __syncthreads();
#pragma unroll
        for (int i = 0; i < 2; ++i) {
            const int row = sr + i * 32;
            *(uint4*)(&Ks[row][sc])  = *(const uint4*)(Kk + head_off + (size_t)(kt + row) * HDIM + sc);
            *(uint4*)(&Vts[row][sc]) = *(const uint4*)(Vt + head_off + (size_t)row * L_SEQ + kt + sc);
        }
        __syncthreads();

        floatx4 s[4][2] = {};
#pragma unroll
        for (int ds = 0; ds < 2; ++ds)
#pragma unroll
            for (int jt = 0; jt < 4; ++jt) {
                const bf16x8 kf = *(const bf16x8*)(&Ks[jt*16 + l16][ds*32 + quad*8]);
                s[jt][0] = __builtin_amdgcn_mfma_f32_16x16x32_bf16(kf, qf[0][ds], s[jt][0], 0, 0, 0);
                s[jt][1] = __builtin_amdgcn_mfma_f32_16x16x32_bf16(kf, qf[1][ds], s[jt][1], 0, 0, 0);
            }

#pragma unroll
        for (int nf = 0; nf < 2; ++nf)
#pragma unroll
            for (int jt = 0; jt < 4; ++jt) {
                const float p0 = exp2f(s[jt][nf][0]);
                const float p1 = exp2f(s[jt][nf][1]);
                const float p2 = exp2f(s[jt][nf][2]);
                const float p3 = exp2f(s[jt][nf][3]);
                l_i[nf] += (p0 + p1) + (p2 + p3);
                uint2 pk;
                pk.x = __builtin_amdgcn_perm(fbits(p1), fbits(p0), 0x07060302u);
                pk.y = __builtin_amdgcn_perm(fbits(p3), fbits(p2), 0x07060302u);
                *(uint2*)(&Ps[w][nf*16 + l16][jt*16 + quad*4]) = pk;
            }

#pragma unroll
        for (int kk = 0; kk < 2; ++kk) {
            const bf16x8 pf0 = *(const bf16x8*)(&Ps[w][l16]     [kk*32 + quad*8]);
            const bf16x8 pf1 = *(const bf16x8*)(&Ps[w][16 + l16][kk*32 + quad*8]);
#pragma unroll
            for (int dt = 0; dt < 4; ++dt) {
                const bf16x8 vf = *(const bf16x8*)(&Vts[dt*16 + l16][kk*32 + quad*8]);
                o[dt][0] = __builtin_amdgcn_mfma_f32_16x16x32_bf16(vf, pf0, o[dt][0], 0, 0, 0);
                o[dt][1] = __builtin_amdgcn_mfma_f32_16x16x32_bf16(vf, pf1, o[dt][1], 0, 0, 0);
            }
        }
    }

    unsigned short* Op = Opart + (size_t)ks * ROWS * DIM;
#pragma unroll
    for (int nf = 0; nf < 2; ++nf) {
        float l = l_i[nf];
        l += __shfl_xor(l, 16, 64);
        l += __shfl_xor(l, 32, 64);
        const int q = q_base + nf*16 + l16;
        if (quad == 0)
            Lpart[((size_t)ks * 32 + bh) * L_SEQ + q] = l;
#pragma unroll
        for (int dt = 0; dt < 4; ++dt) {
            ushort4 ov;
            ov.x = f2bf(o[dt][nf][0]); ov.y = f2bf(o[dt][nf][1]);
            ov.z = f2bf(o[dt][nf][2]); ov.w = f2bf(o[dt][nf][3]);
            *(ushort4*)(Op + (size_t)(q * BATCH + b) * DIM + h * HDIM + dt*16 + quad*4) = ov;
        }
    }
}

// ---------------------------------------------------------------------------
// Merge: aw[row][col] = (O0+O1) / (l0+l1), bf16. One block per row.
// ---------------------------------------------------------------------------
__global__ __launch_bounds__(256)
void attn_merge(const unsigned short* __restrict__ Opart,
                const float* __restrict__ Lpart,
                unsigned short* __restrict__ Aout)
{
    const int row = blockIdx.x;           // 0..4095 (= q*BATCH + b)
    const int q = row >> 1, b = row & 1;
    const int t = threadIdx.x;
    const int col = t * 4;
    const int h = col >> 6;
    const int bh = b * 16 + h;
    const float l0 = Lpart[(size_t)bh * L_SEQ + q];
    const float l1 = Lpart[((size_t)32 + bh) * L_SEQ + q];
    const float inv = 1.0f / (l0 + l1);
    const ushort4 o0 = *(const ushort4*)(Opart + (size_t)row * DIM + col);
    const ushort4 o1 = *(const ushort4*)(Opart + (size_t)ROWS * DIM + (size_t)row * DIM + col);
    ushort4 ov;
    ov.x = f2bf((bf2f(o0.x) + bf2f(o1.x)) * inv);
    ov.y = f2bf((bf2f(o0.y) + bf2f(o1.y)) * inv);
    ov.z = f2bf((bf2f(o0.z) + bf2f(o1.z)) * inv);
    ov.w = f2bf((bf2f(o0.w) + bf2f(o1.w)) * inv);
    *(ushort4*)(Aout + (size_t)row * DIM + col) = ov;
}

// ---------------------------------------------------------------------------
// Launch
// ---------------------------------------------------------------------------
extern "C" void kernel_launch(void* const* d_in, const int* in_sizes, int n_in,
                              void* d_out, int out_size, void* d_ws, size_t ws_size,
                              hipStream_t stream)
{
    const float* x      = (const float*)d_in[0];
    const float* ln1_g  = (const float*)d_in[1];
    const float* ln1_b  = (const float*)d_in[2];
    const float* w_attn = (const float*)d_in[3];
    const float* b_attn = (const float*)d_in[4];
    const float* w_proj = (const float*)d_in[5];
    const float* b_proj = (const float*)d_in[6];
    const float* ln2_g  = (const float*)d_in[7];
    const float* ln2_b  = (const float*)d_in[8];
    const float* w_fc   = (const float*)d_in[9];
    const float* b_fc   = (const float*)d_in[10];
    const float* w_out  = (const float*)d_in[11];
    const float* b_out  = (const float*)d_in[12];

    char* ws = (char*)d_ws;
    unsigned short* watT   = (unsigned short*)(ws + 0);           // [3072,1024] bf16
    unsigned short* wprojT = (unsigned short*)(ws + 6291456);     // [1024,1024]
    unsigned short* wfcT   = (unsigned short*)(ws + 8388608);     // [4096,1024]
    unsigned short* woutT  = (unsigned short*)(ws + 16777216);    // [1024,4096]
    unsigned short* h      = (unsigned short*)(ws + 25165824);    // [4096,1024]
    unsigned short* qkv    = (unsigned short*)(ws + 33554432);    // [4096,3072]
    // After split/transpose_v, qkv region is dead -> reuse for attn partials:
    unsigned short* opart  = (unsigned short*)(ws + 33554432);    // [2][4096][1024] bf16 (16MB)
    float*          lpart  = (float*)(ws + 50331648);             // [2][32][2048] fp32 (512KB)
    unsigned short* mws    = (unsigned short*)(ws + 33554432);    // [4096,4096] (reuses region later)
    unsigned short* qw     = (unsigned short*)(ws + 58720256);    // [32,2048,64]
    unsigned short* kw     = (unsigned short*)(ws + 67108864);    // [32,2048,64]
    unsigned short* vt     = (unsigned short*)(ws + 75497472);    // [32,64,2048] (transposed V)
    unsigned short* aw     = (unsigned short*)(ws + 83886080);    // [4096,1024]
    unsigned short* x2     = (unsigned short*)(ws + 92274688);    // [4096,1024] bf16 residual stream
    // split-K partial for the out GEMM: 16MB fp32, reuses vt+aw (dead at step 9)
    float*          kpart  = (float*)(ws + 75497472);             // [4096,1024] fp32

    float* xout    = (float*)d_out;                // [2048,2,1024]
    float* present = (float*)d_out + 4194304;      // [2,2,16,2048,64]

    // 1. all weight transposes (fp32 -> bf16 [N,K])
    transpose_all<<<12288, 256, 0, stream>>>(w_attn, watT, w_proj, wprojT, w_fc, wfcT, w_out, woutT);

    // 2. LN1
    ln_rows<0><<<ROWS, 256, 0, stream>>>(x, ln1_g, ln1_b, h);
    // 3. QKV GEMM -> bf16 (256^2 deep-pipelined, 16x12 = 192 blocks)
    gemm256b<0,0,1,1><<<dim3(192), 512, 0, stream>>>(h, watT, b_attn, nullptr, qkv, nullptr, ROWS, 3*DIM, DIM, 16);
    // 4. split (q scaled, k, present-K) + V transpose (+present-V)
    split_qkv<<<4096, 256, 0, stream>>>(qkv, qw, kw, present);
    transpose_v<<<dim3(32, 32), 256, 0, stream>>>(qkv, vt, present);
    // 5. attention (key-split x2 -> 1024 blocks, 4/CU) + merge
    attn_kernel<<<dim3(16, 2, 32), 256, 0, stream>>>(qw, kw, vt, opart, lpart);
    attn_merge<<<ROWS, 256, 0, stream>>>(opart, lpart, aw);
    // 6. proj + residual -> x2 bf16 (64x128 tiles: 512 blocks)
    gemm_bt<0,1,1,2,1><<<dim3(64, 8), 256, 0, stream>>>(aw, wprojT, b_proj, x, x2, nullptr, ROWS, DIM, DIM);
    // 7. LN2 (bf16 input)
    ln_rows<1><<<ROWS, 256, 0, stream>>>(x2, ln2_g, ln2_b, h);
    // 8. FC + GELU -> bf16 (256^2 deep-pipelined, 16x16 = 256 blocks)
    gemm256b<1,0,1,1><<<dim3(256), 512, 0, stream>>>(h, wfcT, b_fc, nullptr, mws, nullptr, ROWS, DFF_, DIM, 16);
    // 9. out GEMM, 128x128 tile + split-K 2 (grid 32x8x2 = 512 blocks, 2/CU)
    gemm_bt<0,2,0,4,2><<<dim3(32, 8, 2), 256, 0, stream>>>(mws, woutT, b_out, x2, xout, kpart, ROWS, DIM, DFF_);
    splitk_add<<<4096, 256, 0, stream>>>(kpart, xout);
}

// Round 4
// 403.016 us; speedup vs baseline: 1.0701x; 1.0243x over previous
//
#include <hip/hip_runtime.h>
#include <stdint.h>

// Problem constants
#define L_SEQ 2048
#define BATCH 2
#define DIM   1024
#define NH    16
#define HDIM  64
#define DFF_  4096
#define ROWS  (L_SEQ*BATCH)   // 4096 token rows, row index = l*BATCH + b

// softmax scale folded into Q at split time: (1/sqrt(64)) * log2(e)
#define QSCALE 0.18033688011112042f

typedef __attribute__((ext_vector_type(8))) short  bf16x8;
typedef __attribute__((ext_vector_type(4))) float  floatx4;

__device__ __forceinline__ unsigned short f2bf(float f) {
    union { float f; uint32_t u; } x; x.f = f;
    uint32_t r = x.u + 0x7fffu + ((x.u >> 16) & 1u);   // RNE
    return (unsigned short)(r >> 16);
}
__device__ __forceinline__ float bf2f(unsigned short b) {
    union { uint32_t u; float f; } x; x.u = ((uint32_t)b) << 16;
    return x.f;
}
__device__ __forceinline__ uint32_t fbits(float f) {
    union { float f; uint32_t u; } x; x.f = f; return x.u;
}

// async global->LDS, 16B per lane; lds dest = wave-uniform base + lane*16
__device__ __forceinline__ void load_lds16(const unsigned short* g, unsigned short* l) {
    __builtin_amdgcn_global_load_lds(
        (const __attribute__((address_space(1))) unsigned int*)g,
        (__attribute__((address_space(3))) unsigned int*)l, 16, 0, 0);
}

// ---------------------------------------------------------------------------
// All 4 weight transposes in one kernel: fp32 [K,N] -> bf16 [N,K], 32x32 tiles
// ---------------------------------------------------------------------------
__global__ __launch_bounds__(256)
void transpose_all(const float* __restrict__ s0, unsigned short* __restrict__ d0,
                   const float* __restrict__ s1, unsigned short* __restrict__ d1,
                   const float* __restrict__ s2, unsigned short* __restrict__ d2,
                   const float* __restrict__ s3, unsigned short* __restrict__ d3)
{
    const int id = blockIdx.x;
    const float* src; unsigned short* dst; int K, N, local;
    if (id < 3072)      { src = s0; dst = d0; K = 1024; N = 3072; local = id; }
    else if (id < 4096) { src = s1; dst = d1; K = 1024; N = 1024; local = id - 3072; }
    else if (id < 8192) { src = s2; dst = d2; K = 1024; N = 4096; local = id - 4096; }
    else                { src = s3; dst = d3; K = 4096; N = 1024; local = id - 8192; }
    const int nN = N >> 5;
    const int bk = (local / nN) * 32, bn = (local % nN) * 32;

    __shared__ float tile[32][36];
    const int t = threadIdx.x;
    const int r = t >> 3, c4 = (t & 7) * 4;
    *(float4*)&tile[r][c4] = *(const float4*)(src + (size_t)(bk + r) * N + bn + c4);
    __syncthreads();
    ushort4 o;
    o.x = f2bf(tile[c4 + 0][r]);
    o.y = f2bf(tile[c4 + 1][r]);
    o.z = f2bf(tile[c4 + 2][r]);
    o.w = f2bf(tile[c4 + 3][r]);
    *(ushort4*)(dst + (size_t)(bn + r) * K + bk + c4) = o;
}

// ---------------------------------------------------------------------------
// LayerNorm: [4096,1024] fp32 or bf16 input -> bf16 out, one block per row
// ---------------------------------------------------------------------------
template<int INBF16>
__global__ __launch_bounds__(256)
void ln_rows(const void* __restrict__ xin, const float* __restrict__ g,
             const float* __restrict__ bta, unsigned short* __restrict__ out)
{
    const int row = blockIdx.x;
    const int t = threadIdx.x;
    float4 v;
    if (INBF16) {
        const ushort4 u = ((const ushort4*)((const unsigned short*)xin + (size_t)row * DIM))[t];
        v.x = bf2f(u.x); v.y = bf2f(u.y); v.z = bf2f(u.z); v.w = bf2f(u.w);
    } else {
        v = ((const float4*)((const float*)xin + (size_t)row * DIM))[t];
    }
    float s  = v.x + v.y + v.z + v.w;
    float s2 = v.x*v.x + v.y*v.y + v.z*v.z + v.w*v.w;
#pragma unroll
    for (int d = 1; d < 64; d <<= 1) { s += __shfl_xor(s, d, 64); s2 += __shfl_xor(s2, d, 64); }
    __shared__ float ss[4], ss2[4];
    const int w = t >> 6, lane = t & 63;
    if (lane == 0) { ss[w] = s; ss2[w] = s2; }
    __syncthreads();
    s  = ss[0] + ss[1] + ss[2] + ss[3];
    s2 = ss2[0] + ss2[1] + ss2[2] + ss2[3];
    const float mu   = s * (1.0f / DIM);
    const float var  = s2 * (1.0f / DIM) - mu * mu;
    const float rstd = rsqrtf(var + 1e-5f);
    const float4 gv = ((const float4*)g)[t];
    const float4 bv = ((const float4*)bta)[t];
    ushort4 o;
    o.x = f2bf((v.x - mu) * rstd * gv.x + bv.x);
    o.y = f2bf((v.y - mu) * rstd * gv.y + bv.y);
    o.z = f2bf((v.z - mu) * rstd * gv.z + bv.z);
    o.w = f2bf((v.w - mu) * rstd * gv.w + bv.w);
    *(ushort4*)(out + (size_t)row * DIM + t * 4) = o;
}

// ---------------------------------------------------------------------------
// bf16 GEMM, B^T input (Bt [N,K]); C = A@B + bias (+resid) (gelu?)
// MI=4: 128x128 tile; MI=2: 64x128 tile. BK=32, m97 structure.
// RESID: 0=none, 1=fp32, 2=bf16
// SPLITK>1: blockIdx.z = K-slice; kz>0 writes raw fp32 partial.
// ---------------------------------------------------------------------------
template<int GELU, int RESID, int OUTBF16, int MI, int SPLITK>
__global__ __launch_bounds__(256)
void gemm_bt(const unsigned short* __restrict__ A,   // [M,K] bf16
             const unsigned short* __restrict__ Bt,  // [N,K] bf16
             const float* __restrict__ bias,         // [N]
             const void* __restrict__ resid,         // [M,N] fp32/bf16 or null
             void* __restrict__ outp,                // bf16 or fp32 [M,N]
             float* __restrict__ part,               // fp32 partials (SPLITK>1)
             int M, int N, int K)
{
    __shared__ unsigned short As[MI * 32 * 32];   // flat, unpadded
    __shared__ unsigned short Bs[128 * 32];
    const int t = threadIdx.x;
    const int w = t >> 6, lane = t & 63;
    const int quad = lane >> 4, l16 = lane & 15;
    const int wm = (w >> 1) * (MI * 16), wn = (w & 1) * 64;
    const int bm = blockIdx.x * (MI * 32), bn = blockIdx.y * 128;

    const int srow = lane >> 2;
    const int scol = (lane & 3) * 8;

    const unsigned short* Ab = A  + (size_t)bm * K;
    const unsigned short* Bb = Bt + (size_t)bn * K;

    floatx4 acc[MI][4] = {};

    const int kspan = (SPLITK > 1) ? (K / SPLITK) : K;
    const int k0    = (SPLITK > 1) ? blockIdx.z * kspan : 0;

    for (int kc = k0; kc < k0 + kspan; kc += 32) {
        __syncthreads();
#pragma unroll
        for (int i = 0; i < MI / 2; ++i) {
            const int r0 = (i * 4 + w) * 16;
            load_lds16(Ab + (size_t)(r0 + srow) * K + kc + scol, As + r0 * 32);
        }
#pragma unroll
        for (int i = 0; i < 2; ++i) {
            const int r0 = (i * 4 + w) * 16;
            load_lds16(Bb + (size_t)(r0 + srow) * K + kc + scol, Bs + r0 * 32);
        }
        __syncthreads();
        bf16x8 af[MI], bf[4];
#pragma unroll
        for (int i = 0; i < MI; ++i) af[i] = *(const bf16x8*)(As + (wm + i*16 + l16) * 32 + quad * 8);
#pragma unroll
        for (int j = 0; j < 4; ++j) bf[j] = *(const bf16x8*)(Bs + (wn + j*16 + l16) * 32 + quad * 8);
#pragma unroll
        for (int i = 0; i < MI; ++i)
#pragma unroll
            for (int j = 0; j < 4; ++j)
                acc[i][j] = __builtin_amdgcn_mfma_f32_16x16x32_bf16(af[i], bf[j], acc[i][j], 0, 0, 0);
    }

    if (SPLITK > 1 && blockIdx.z > 0) {
        float* po = part + (size_t)(blockIdx.z - 1) * ((size_t)M * N);
#pragma unroll
        for (int i = 0; i < MI; ++i)
#pragma unroll
            for (int j = 0; j < 4; ++j) {
                const int col = bn + wn + j*16 + l16;
#pragma unroll
                for (int r = 0; r < 4; ++r) {
                    const int row = bm + wm + i*16 + quad*4 + r;
                    po[(size_t)row * N + col] = acc[i][j][r];
                }
            }
        return;
    }

#pragma unroll
    for (int i = 0; i < MI; ++i) {
#pragma unroll
        for (int j = 0; j < 4; ++j) {
            const int col = bn + wn + j*16 + l16;
            const float bv = bias[col];
#pragma unroll
            for (int r = 0; r < 4; ++r) {
                const int row = bm + wm + i*16 + quad*4 + r;
                float v = acc[i][j][r] + bv;
                if (RESID == 1) v += ((const float*)resid)[(size_t)row * N + col];
                if (RESID == 2) v += bf2f(((const unsigned short*)resid)[(size_t)row * N + col]);
                if (GELU) {
                    const float u = v;
                    float c = 2.302204225929898f * (u + 0.044715f * u * u * u);
                    c = fminf(c, 80.f);
                    const float e = exp2f(c);
                    v = u * (e / (1.0f + e));
                }
                if (OUTBF16) ((unsigned short*)outp)[(size_t)row * N + col] = f2bf(v);
                else         ((float*)outp)[(size_t)row * N + col] = v;
            }
        }
    }
}

// ---------------------------------------------------------------------------
// 256x256-tile deep-pipelined GEMM v2, BK=32, 64 KiB STATIC LDS.
// 512 threads = 8 waves (2 M x 4 N), per-wave 128x64 output, acc[8][4].
// LDS: 2 buffers x (A 16KB + B 16KB), XOR-swizzled (SWZ32) within each
//   16KB region; staged via global_load_lds with linear LDS dest +
//   pre-swizzled global source (rule #21; refcheck'd R3, bank-conflict 0).
// A rows are BAND-PERMUTED in LDS so the P0-consumed rows (orig
//   wr*128+[0,64)) occupy LDS rows [0,128) and P1-consumed rows (orig
//   wr*128+64+[0,64)) occupy LDS rows [128,256):
//     permuted rp = band*64+within, band = {0: orig 0-63, 1: 128-191,
//     2: 64-127, 3: 192-255};  orig = within + (band&1)*128 + (band>>1)*64.
//   This makes each contiguous 8KB staging half correspond exactly to one
//   compute phase's reads -> all stages target regions whose last reader
//   is >=1 barrier in the past (no LDS read/write races).
// Calendar (i+2-deep, counted vmcnt(3) per tile, never 0 in steady state):
//   P0(i): STAGE A(i+1)-P1half -> other buf (freed at P1(i-1));
//          ds_read af-P0band + bf-all; bar; MFMA-lo; bar.
//   P1(i): STAGE B(i+2)-both + A(i+2)-P0half -> current buf (freed P0(i));
//          ds_read af-P1band; bar; MFMA-hi; vmcnt(3); bar.
// Budgets: B/A-P0 ~650cy, A-P1 ~360cy (vs 230cy in the R3 version).
// Requires M%256==0, N%256==0, K/SPLITK%64==0, gridDim.x%8==0.
// ---------------------------------------------------------------------------
#define SWZ32(p) ((p) ^ ((((p) >> 7) & 3) << 4))

template<int GELU, int RESID, int OUTBF16, int SPLITK>
__global__ __launch_bounds__(512, 2)
void gemm256b(const unsigned short* __restrict__ A,   // [M,K] bf16
              const unsigned short* __restrict__ Bt,  // [N,K] bf16
              const float* __restrict__ bias,         // [N]
              const void* __restrict__ resid,         // [M,N] or null
              void* __restrict__ outp,                // bf16 or fp32 [M,N]
              float* __restrict__ part,               // fp32 partials
              int M, int N, int K, int nbx)
{
    __shared__ unsigned short lds[32768];            // 64 KiB exactly
    const int t = threadIdx.x;
    const int w = t >> 6, lane = t & 63;
    const int quad = lane >> 4, l16 = lane & 15;
    const int wr = w >> 2, wc = w & 3;

    // bijective XCD swizzle (gridDim.x % 8 == 0)
    const int nwg = gridDim.x;
    const int cpx = nwg >> 3;
    const int bid = (blockIdx.x & 7) * cpx + (blockIdx.x >> 3);
    const int bm = (bid % nbx) * 256, bn = (bid / nbx) * 256;

    const unsigned short* Ab = A  + (size_t)bm * K;
    const unsigned short* Bb = Bt + (size_t)bn * K;

    // staging source offsets for an 8KB half staged at half-local byte t*16
    // (SWZ32 is closed within each 8KB half: it only flips bits 4-5).
    const int sh   = SWZ32(t * 16);          // [0,8192)
    const int rp0  = sh >> 6;                // swizzled row within half [0,128)
    const int colE = (sh & 63) >> 1;         // element col within BK=32
    const int w0 = rp0 & 63, hb = rp0 >> 6;  // band-within / band-half bit
    // B: linear rows per half
    const size_t bOff0 = (size_t)rp0 * K + colE;
    const size_t bOff1 = (size_t)(128 + rp0) * K + colE;
    // A: band-permuted rows (see header comment)
    const size_t aOff0 = (size_t)(w0 + hb * 128)      * K + colE;  // bands 0,1
    const size_t aOff1 = (size_t)(w0 + hb * 128 + 64) * K + colE;  // bands 2,3

    // one 8KB half: 1 VMEM instr/wave; dstE_ in ELEMENTS
#define STGH(dstE_, srcp_, kta_, off_) \
    load_lds16((srcp_) + (size_t)(kta_) * 32 + (off_), lds + (dstE_) + w * 512)
#define BARF    do { __builtin_amdgcn_s_barrier(); asm volatile("" ::: "memory"); } while (0)
#define CL_PRE  do { asm volatile("s_waitcnt lgkmcnt(0)" ::: "memory");    \
                     __builtin_amdgcn_sched_barrier(0);                    \
                     __builtin_amdgcn_s_setprio(1); } while (0)
#define CL_POST do { __builtin_amdgcn_s_setprio(0);                        \
                     __builtin_amdgcn_sched_barrier(0); } while (0)

    floatx4 acc[8][4] = {};
    const int nt  = ((SPLITK > 1) ? (K / SPLITK) : K) >> 5;
    const int ktb = (SPLITK > 1) ? blockIdx.y * nt : 0;

    // prologue: tiles 0,1 fully staged; wait tile0 (vmcnt(4) leaves tile1 in flight)
    STGH(0,     Ab, ktb,     aOff0);  STGH(4096,  Ab, ktb,     aOff1);
    STGH(8192,  Bb, ktb,     bOff0);  STGH(12288, Bb, ktb,     bOff1);
    STGH(16384, Ab, ktb + 1, aOff0);  STGH(20480, Ab, ktb + 1, aOff1);
    STGH(24576, Bb, ktb + 1, bOff0);  STGH(28672, Bb, ktb + 1, bOff1);
    asm volatile("s_waitcnt vmcnt(4)" ::: "memory");
    BARF;

    for (int i = 0; i < nt; ++i) {
        const int cb = i & 1;
        const int i1 = (i + 1 < nt) ? i + 1 : nt - 1;
        const int i2 = (i + 2 < nt) ? i + 2 : nt - 1;
        const int oA = cb * 16384, oB = oA + 8192;
        const int xA = (cb ^ 1) * 16384;
        const char* Abase = (const char*)lds + cb * 32768;
        const char* Bbase = Abase + 16384;
        bf16x8 af[4], bf[4];

        // ---- P0: stage A(i+1)-P1half -> other buf; read af-P0band + bf-all ----
        STGH(xA + 4096, Ab, ktb + i1, aOff1);
#pragma unroll
        for (int mi = 0; mi < 4; ++mi) {
            const int p = (wr * 64 + mi * 16 + l16) * 64 + quad * 16;   // permuted rows [0,128)
            af[mi] = *(const bf16x8*)(Abase + SWZ32(p));
        }
#pragma unroll
        for (int nj = 0; nj < 4; ++nj) {
            const int p = (wc * 64 + nj * 16 + l16) * 64 + quad * 16;
            bf[nj] = *(const bf16x8*)(Bbase + SWZ32(p));
        }
        BARF;
        CL_PRE;
#pragma unroll
        for (int mi = 0; mi < 4; ++mi)
#pragma unroll
            for (int nj = 0; nj < 4; ++nj)
                acc[mi][nj] = __builtin_amdgcn_mfma_f32_16x16x32_bf16(af[mi], bf[nj], acc[mi][nj], 0, 0, 0);
        CL_POST;
        BARF;

        // ---- P1: stage B(i+2)+A(i+2)-P0half -> current buf; read af-P1band ----
        STGH(oB,        Bb, ktb + i2, bOff0);
        STGH(oB + 4096, Bb, ktb + i2, bOff1);
        STGH(oA,        Ab, ktb + i2, aOff0);
#pragma unroll
        for (int mi = 0; mi < 4; ++mi) {
            const int p = (128 + wr * 64 + mi * 16 + l16) * 64 + quad * 16; // permuted rows [128,256)
            af[mi] = *(const bf16x8*)(Abase + SWZ32(p));
        }
        BARF;
        CL_PRE;
#pragma unroll
        for (int mi = 0; mi < 4; ++mi)
#pragma unroll
            for (int nj = 0; nj < 4; ++nj)
                acc[4 + mi][nj] = __builtin_amdgcn_mfma_f32_16x16x32_bf16(af[mi], bf[nj], acc[4 + mi][nj], 0, 0, 0);
        CL_POST;
        // tile boundary: waits exactly the 4 halves of tile (i+1); leaves
        // the 3 halves of tile (i+2) staged so far in flight.
        asm volatile("s_waitcnt vmcnt(3)" ::: "memory");
        BARF;
    }

    if (SPLITK > 1 && blockIdx.y > 0) {
        float* po = part + (size_t)(blockIdx.y - 1) * ((size_t)M * N);
#pragma unroll
        for (int mi = 0; mi < 8; ++mi)
#pragma unroll
            for (int nj = 0; nj < 4; ++nj) {
                const int col = bn + wc * 64 + nj * 16 + l16;
#pragma unroll
                for (int r = 0; r < 4; ++r) {
                    const int row = bm + wr * 128 + mi * 16 + quad * 4 + r;
                    po[(size_t)row * N + col] = acc[mi][nj][r];
                }
            }
        return;
    }

#pragma unroll
    for (int mi = 0; mi < 8; ++mi) {
#pragma unroll
        for (int nj = 0; nj < 4; ++nj) {
            const int col = bn + wc * 64 + nj * 16 + l16;
            const float bv = bias[col];
#pragma unroll
            for (int r = 0; r < 4; ++r) {
                const int row = bm + wr * 128 + mi * 16 + quad * 4 + r;
                float v = acc[mi][nj][r] + bv;
                if (RESID == 1) v += ((const float*)resid)[(size_t)row * N + col];
                if (RESID == 2) v += bf2f(((const unsigned short*)resid)[(size_t)row * N + col]);
                if (GELU) {
                    const float u = v;
                    float c = 2.302204225929898f * (u + 0.044715f * u * u * u);
                    c = fminf(c, 80.f);
                    const float e = exp2f(c);
                    v = u * (e / (1.0f + e));
                }
                if (OUTBF16) ((unsigned short*)outp)[(size_t)row * N + col] = f2bf(v);
                else         ((float*)outp)[(size_t)row * N + col] = v;
            }
        }
    }
#undef STGH
#undef BARF
#undef CL_PRE
#undef CL_POST
}

// ---------------------------------------------------------------------------
// split-K merge: outp[i] += part[i], fp32, float4-vectorized
// ---------------------------------------------------------------------------
__global__ __launch_bounds__(256)
void splitk_add(const float* __restrict__ part, float* __restrict__ outp)
{
    const size_t i = ((size_t)blockIdx.x * 256 + threadIdx.x) * 4;
    float4 a = *(const float4*)(outp + i);
    const float4 p = *(const float4*)(part + i);
    a.x += p.x; a.y += p.y; a.z += p.z; a.w += p.w;
    *(float4*)(outp + i) = a;
}

// ---------------------------------------------------------------------------
// split qkv -> q (scaled by QSCALE), k [B*H, L, 64] bf16 + present-K fp32
// ---------------------------------------------------------------------------
__global__ __launch_bounds__(256)
void split_qkv(const unsigned short* __restrict__ qkv,
               unsigned short* __restrict__ q, unsigned short* __restrict__ k,
               float* __restrict__ present)
{
    const size_t idx = (size_t)blockIdx.x * 256 + threadIdx.x; // [2 sel][32 bh][2048 l][8 grp]
    const int g8  = idx & 7;
    const int l   = (idx >> 3) & 2047;
    const int bh  = (idx >> 14) & 31;
    const int sel = (int)(idx >> 19);
    const int b = bh >> 4, h = bh & 15;
    const unsigned short* src = qkv + (size_t)(l * BATCH + b) * (3 * DIM) + sel * DIM + h * HDIM + g8 * 8;
    const uint4 val = *(const uint4*)src;
    const unsigned short* sv = (const unsigned short*)&val;
    if (sel == 0) {
        unsigned short ov[8];
#pragma unroll
        for (int j = 0; j < 8; ++j) ov[j] = f2bf(bf2f(sv[j]) * QSCALE);
        *(uint4*)(q + ((size_t)bh * L_SEQ + l) * HDIM + g8 * 8) = *(uint4*)ov;
    } else {
        *(uint4*)(k + ((size_t)bh * L_SEQ + l) * HDIM + g8 * 8) = val;
        float* p = present + (((size_t)b * NH + h) * L_SEQ + l) * HDIM + (size_t)g8 * 8;
        float4 f0, f1;
        f0.x = bf2f(sv[0]); f0.y = bf2f(sv[1]); f0.z = bf2f(sv[2]); f0.w = bf2f(sv[3]);
        f1.x = bf2f(sv[4]); f1.y = bf2f(sv[5]); f1.z = bf2f(sv[6]); f1.w = bf2f(sv[7]);
        ((float4*)p)[0] = f0; ((float4*)p)[1] = f1;
    }
}

// ---------------------------------------------------------------------------
// V transpose: qkv v-columns -> vt [bh][64 d][2048 l] bf16, + present-V fp32
// ---------------------------------------------------------------------------
__global__ __launch_bounds__(256)
void transpose_v(const unsigned short* __restrict__ qkv, unsigned short* __restrict__ vt,
                 float* __restrict__ present)
{
    __shared__ unsigned short tile[64][72];
    const int lt = blockIdx.x;            // 0..31
    const int bh = blockIdx.y;            // 0..31
    const int b = bh >> 4, h = bh & 15;
    const int t = threadIdx.x;
#pragma unroll
    for (int i = 0; i < 2; ++i) {
        const int idx = i * 256 + t;
        const int l = idx >> 3, c = (idx & 7) * 8;
        const uint4 val =
            *(const uint4*)(qkv + (size_t)((lt * 64 + l) * BATCH + b) * (3 * DIM) + 2 * DIM + h * HDIM + c);
        *(uint4*)(&tile[l][c]) = val;
        const unsigned short* sv = (const unsigned short*)&val;
        float* p = present + ((((size_t)BATCH + b) * NH + h) * L_SEQ + lt * 64 + l) * HDIM + c;
        float4 f0, f1;
        f0.x = bf2f(sv[0]); f0.y = bf2f(sv[1]); f0.z = bf2f(sv[2]); f0.w = bf2f(sv[3]);
        f1.x = bf2f(sv[4]); f1.y = bf2f(sv[5]); f1.z = bf2f(sv[6]); f1.w = bf2f(sv[7]);
        ((float4*)p)[0] = f0; ((float4*)p)[1] = f1;
    }
    __syncthreads();
#pragma unroll
    for (int i = 0; i < 2; ++i) {
        const int idx = i * 256 + t;
        const int d = idx >> 3, l0 = (idx & 7) * 8;
        const int kk = l0 >> 3;
        ushort4 o[2];
        unsigned short* ov = (unsigned short*)o;
#pragma unroll
        for (int jj = 0; jj < 8; ++jj) {
            const int j = (jj + kk) & 7;
            ov[j] = tile[l0 + j][d];
        }
        *(uint4*)(vt + ((size_t)bh * HDIM + d) * L_SEQ + lt * 64 + l0) = *(uint4*)o;
    }
}

// ---------------------------------------------------------------------------
// Flash attention, S^T + static-max softmax, KEY-SPLIT 2-way.
// ---------------------------------------------------------------------------
__global__ __launch_bounds__(256, 4)
void attn_kernel(const unsigned short* __restrict__ Q,
                 const unsigned short* __restrict__ Kk,
                 const unsigned short* __restrict__ Vt,
                 unsigned short* __restrict__ Opart,   // [2][4096][1024] bf16 unnormalized
                 float* __restrict__ Lpart)            // [2][32][2048] fp32
{
    const int qt = blockIdx.x;            // 0..15  (128 q rows each)
    const int ks = blockIdx.y;            // 0..1   (key split)
    const int bh = blockIdx.z;            // 0..31
    const int b = bh >> 4, h = bh & 15;
    const int t = threadIdx.x, w = t >> 6, lane = t & 63;
    const int quad = lane >> 4, l16 = lane & 15;

    __shared__ unsigned short Ks[64][72];      // [key][d]
    __shared__ unsigned short Vts[64][72];     // [d][key]
    __shared__ unsigned short Ps[4][32][72];   // per-wave P^T as [q][key]

    const size_t head_off = (size_t)bh * L_SEQ * HDIM;
    const int q_base = qt * 128 + w * 32;
    const int kt0 = ks * 1024;

    bf16x8 qf[2][2];
#pragma unroll
    for (int nf = 0; nf < 2; ++nf)
#pragma unroll
        for (int ds = 0; ds < 2; ++ds)
            qf[nf][ds] = *(const bf16x8*)(Q + head_off + (size_t)(q_base + nf*16 + l16) * HDIM + ds*32 + quad*8);

    const int sr = t >> 3;
    const int sc = (t & 7) * 8;

    floatx4 o[4][2] = {};              // O^T[d=dt*16+quad*4+r][q=nf*16+l16]
    float l_i[2] = {0.f, 0.f};

    for (int kt = kt0; kt < kt0 + 1024; kt += 64) {
        __syncthreads();
#pragma unroll
        for (int i = 0; i < 2; ++i) {
            const int row = sr + i * 32;
            *(uint4*)(&Ks[row][sc])  = *(const uint4*)(Kk + head_off + (size_t)(kt + row) * HDIM + sc);
            *(uint4*)(&Vts[row][sc]) = *(const uint4*)(Vt + head_off + (size_t)row * L_SEQ + kt + sc);
        }
        __syncthreads();

        floatx4 s[4][2] = {};
#pragma unroll
        for (int ds = 0; ds < 2; ++ds)
#pragma unroll
            for (int jt = 0; jt < 4; ++jt) {
                const bf16x8 kf = *(const bf16x8*)(&Ks[jt*16 + l16][ds*32 + quad*8]);
                s[jt][0] = __builtin_amdgcn_mfma_f32_16x16x32_bf16(kf, qf[0][ds], s[jt][0], 0, 0, 0);
                s[jt][1] = __builtin_amdgcn_mfma_f32_16x16x32_bf16(kf, qf[1][ds], s[jt][1], 0, 0, 0);
            }

#pragma unroll
        for (int nf = 0; nf < 2; ++nf)
#pragma unroll
            for (int jt = 0; jt < 4; ++jt) {
                const float p0 = exp2f(s[jt][nf][0]);
                const float p1 = exp2f(s[jt][nf][1]);
                const float p2 = exp2f(s[jt][nf][2]);
                const float p3 = exp2f(s[jt][nf][3]);
                l_i[nf] += (p0 + p1) + (p2 + p3);
                uint2 pk;
                pk.x = __builtin_amdgcn_perm(fbits(p1), fbits(p0), 0x07060302u);
                pk.y = __builtin_amdgcn_perm(fbits(p3), fbits(p2), 0x07060302u);
                *(uint2*)(&Ps[w][nf*16 + l16][jt*16 + quad*4]) = pk;
            }

#pragma unroll
        for (int kk = 0; kk < 2; ++kk) {
            const bf16x8 pf0 = *(const bf16x8*)(&Ps[w][l16]     [kk*32 + quad*8]);
            const bf16x8 pf1 = *(const bf16x8*)(&Ps[w][16 + l16][kk*32 + quad*8]);
#pragma unroll
            for (int dt = 0; dt < 4; ++dt) {
                const bf16x8 vf = *(const bf16x8*)(&Vts[dt*16 + l16][kk*32 + quad*8]);
                o[dt][0] = __builtin_amdgcn_mfma_f32_16x16x32_bf16(vf, pf0, o[dt][0], 0, 0, 0);
                o[dt][1] = __builtin_amdgcn_mfma_f32_16x16x32_bf16(vf, pf1, o[dt][1], 0, 0, 0);
            }
        }
    }

    unsigned short* Op = Opart + (size_t)ks * ROWS * DIM;
#pragma unroll
    for (int nf = 0; nf < 2; ++nf) {
        float l = l_i[nf];
        l += __shfl_xor(l, 16, 64);
        l += __shfl_xor(l, 32, 64);
        const int q = q_base + nf*16 + l16;
        if (quad == 0)
            Lpart[((size_t)ks * 32 + bh) * L_SEQ + q] = l;
#pragma unroll
        for (int dt = 0; dt < 4; ++dt) {
            ushort4 ov;
            ov.x = f2bf(o[dt][nf][0]); ov.y = f2bf(o[dt][nf][1]);
            ov.z = f2bf(o[dt][nf][2]); ov.w = f2bf(o[dt][nf][3]);
            *(ushort4*)(Op + (size_t)(q * BATCH + b) * DIM + h * HDIM + dt*16 + quad*4) = ov;
        }
    }
}

// ---------------------------------------------------------------------------
// Merge: aw[row][col] = (O0+O1) / (l0+l1), bf16. One block per row.
// ---------------------------------------------------------------------------
__global__ __launch_bounds__(256)
void attn_merge(const unsigned short* __restrict__ Opart,
                const float* __restrict__ Lpart,
                unsigned short* __restrict__ Aout)
{
    const int row = blockIdx.x;           // 0..4095 (= q*BATCH + b)
    const int q = row >> 1, b = row & 1;
    const int t = threadIdx.x;
    const int col = t * 4;
    const int h = col >> 6;
    const int bh = b * 16 + h;
    const float l0 = Lpart[(size_t)bh * L_SEQ + q];
    const float l1 = Lpart[((size_t)32 + bh) * L_SEQ + q];
    const float inv = 1.0f / (l0 + l1);
    const ushort4 o0 = *(const ushort4*)(Opart + (size_t)row * DIM + col);
    const ushort4 o1 = *(const ushort4*)(Opart + (size_t)ROWS * DIM + (size_t)row * DIM + col);
    ushort4 ov;
    ov.x = f2bf((bf2f(o0.x) + bf2f(o1.x)) * inv);
    ov.y = f2bf((bf2f(o0.y) + bf2f(o1.y)) * inv);
    ov.z = f2bf((bf2f(o0.z) + bf2f(o1.z)) * inv);
    ov.w = f2bf((bf2f(o0.w) + bf2f(o1.w)) * inv);
    *(ushort4*)(Aout + (size_t)row * DIM + col) = ov;
}

// ---------------------------------------------------------------------------
// Launch
// ---------------------------------------------------------------------------
extern "C" void kernel_launch(void* const* d_in, const int* in_sizes, int n_in,
                              void* d_out, int out_size, void* d_ws, size_t ws_size,
                              hipStream_t stream)
{
    const float* x      = (const float*)d_in[0];
    const float* ln1_g  = (const float*)d_in[1];
    const float* ln1_b  = (const float*)d_in[2];
    const float* w_attn = (const float*)d_in[3];
    const float* b_attn = (const float*)d_in[4];
    const float* w_proj = (const float*)d_in[5];
    const float* b_proj = (const float*)d_in[6];
    const float* ln2_g  = (const float*)d_in[7];
    const float* ln2_b  = (const float*)d_in[8];
    const float* w_fc   = (const float*)d_in[9];
    const float* b_fc   = (const float*)d_in[10];
    const float* w_out  = (const float*)d_in[11];
    const float* b_out  = (const float*)d_in[12];

    char* ws = (char*)d_ws;
    unsigned short* watT   = (unsigned short*)(ws + 0);           // [3072,1024] bf16
    unsigned short* wprojT = (unsigned short*)(ws + 6291456);     // [1024,1024]
    unsigned short* wfcT   = (unsigned short*)(ws + 8388608);     // [4096,1024]
    unsigned short* woutT  = (unsigned short*)(ws + 16777216);    // [1024,4096]
    unsigned short* h      = (unsigned short*)(ws + 25165824);    // [4096,1024]
    unsigned short* qkv    = (unsigned short*)(ws + 33554432);    // [4096,3072]
    // After split/transpose_v, qkv region is dead -> reuse for attn partials:
    unsigned short* opart  = (unsigned short*)(ws + 33554432);    // [2][4096][1024] bf16 (16MB)
    float*          lpart  = (float*)(ws + 50331648);             // [2][32][2048] fp32 (512KB)
    unsigned short* mws    = (unsigned short*)(ws + 33554432);    // [4096,4096] (reuses region later)
    unsigned short* qw     = (unsigned short*)(ws + 58720256);    // [32,2048,64]
    unsigned short* kw     = (unsigned short*)(ws + 67108864);    // [32,2048,64]
    unsigned short* vt     = (unsigned short*)(ws + 75497472);    // [32,64,2048] (transposed V)
    unsigned short* aw     = (unsigned short*)(ws + 83886080);    // [4096,1024]
    unsigned short* x2     = (unsigned short*)(ws + 92274688);    // [4096,1024] bf16 residual stream
    // split-K partial for the out GEMM: 16MB fp32, reuses vt+aw (dead at step 9)
    float*          kpart  = (float*)(ws + 75497472);             // [4096,1024] fp32

    float* xout    = (float*)d_out;                // [2048,2,1024]
    float* present = (float*)d_out + 4194304;      // [2,2,16,2048,64]

    // 1. all weight transposes (fp32 -> bf16 [N,K])
    transpose_all<<<12288, 256, 0, stream>>>(w_attn, watT, w_proj, wprojT, w_fc, wfcT, w_out, woutT);

    // 2. LN1
    ln_rows<0><<<ROWS, 256, 0, stream>>>(x, ln1_g, ln1_b, h);
    // 3. QKV GEMM -> bf16 (256^2 deep-pipelined v2, 16x12 = 192 blocks)
    gemm256b<0,0,1,1><<<dim3(192), 512, 0, stream>>>(h, watT, b_attn, nullptr, qkv, nullptr, ROWS, 3*DIM, DIM, 16);
    // 4. split (q scaled, k, present-K) + V transpose (+present-V)
    split_qkv<<<4096, 256, 0, stream>>>(qkv, qw, kw, present);
    transpose_v<<<dim3(32, 32), 256, 0, stream>>>(qkv, vt, present);
    // 5. attention (key-split x2 -> 1024 blocks, 4/CU) + merge
    attn_kernel<<<dim3(16, 2, 32), 256, 0, stream>>>(qw, kw, vt, opart, lpart);
    attn_merge<<<ROWS, 256, 0, stream>>>(opart, lpart, aw);
    // 6. proj + residual -> x2 bf16 (64x128 tiles: 512 blocks)
    gemm_bt<0,1,1,2,1><<<dim3(64, 8), 256, 0, stream>>>(aw, wprojT, b_proj, x, x2, nullptr, ROWS, DIM, DIM);
    // 7. LN2 (bf16 input)
    ln_rows<1><<<ROWS, 256, 0, stream>>>(x2, ln2_g, ln2_b, h);
    // 8. FC + GELU -> bf16 (256^2 deep-pipelined v2, 16x16 = 256 blocks)
    gemm256b<1,0,1,1><<<dim3(256), 512, 0, stream>>>(h, wfcT, b_fc, nullptr, mws, nullptr, ROWS, DFF_, DIM, 16);
    // 9. out GEMM, 128x128 tile + split-K 2 (grid 32x8x2 = 512 blocks, 2/CU)
    gemm_bt<0,2,0,4,2><<<dim3(32, 8, 2), 256, 0, stream>>>(mws, woutT, b_out, x2, xout, kpart, ROWS, DIM, DFF_);
    splitk_add<<<4096, 256, 0, stream>>>(kpart, xout);
}